// Round 17
// baseline (879.098 us; speedup 1.0000x reference)
//
#include <hip/hip_runtime.h>

typedef unsigned int uint;
typedef unsigned short ushort;
typedef __attribute__((ext_vector_type(8))) short bf16x8;
typedef __attribute__((ext_vector_type(4))) float f32x4;

#define GLD_LDS(g, l) __builtin_amdgcn_global_load_lds( \
    (const __attribute__((address_space(1))) void*)(g), \
    (__attribute__((address_space(3))) void*)(l), 16, 0, 0)

__device__ __forceinline__ ushort f2bf(float f) {
    uint u = __builtin_bit_cast(uint, f);
    u += 0x7fffu + ((u >> 16) & 1u);
    return (ushort)(u >> 16);
}
__device__ __forceinline__ float bf2f(ushort s) {
    uint u = ((uint)s) << 16;
    return __builtin_bit_cast(float, u);
}
__device__ __forceinline__ void wave_sync() {
    asm volatile("s_waitcnt lgkmcnt(0)" ::: "memory");
}
__device__ __forceinline__ float wave_max(float v) {
#pragma unroll
    for (int d = 32; d >= 1; d >>= 1) v = fmaxf(v, __shfl_xor(v, d));
    return v;
}
__device__ __forceinline__ float wave_sum(float v) {
#pragma unroll
    for (int d = 32; d >= 1; d >>= 1) v += __shfl_xor(v, d);
    return v;
}

// ---------------- CSR build ----------------
__global__ void deg_hole_kernel(const int* __restrict__ dst, int* __restrict__ cnt,
                                const int* __restrict__ bat, int* __restrict__ hole,
                                int E, int N) {
    int e = blockIdx.x * 256 + threadIdx.x;
    if (e < E) atomicAdd(&cnt[dst[e]], 1);
    if (e < N) atomicMin(&hole[bat[e]], e);
}

__global__ void scan_kernel(const int* __restrict__ cnt, int* __restrict__ offs, int n) {
    __shared__ int part[1024];
    const int t = threadIdx.x;
    const int strip = (n + 1023) / 1024;
    int s = 0;
    for (int i = 0; i < strip; ++i) {
        int idx = t * strip + i;
        if (idx < n) s += cnt[idx];
    }
    part[t] = s;
    __syncthreads();
    for (int d = 1; d < 1024; d <<= 1) {
        int v = (t >= d) ? part[t - d] : 0;
        __syncthreads();
        part[t] += v;
        __syncthreads();
    }
    int run = (t == 0) ? 0 : part[t - 1];
    for (int i = 0; i < strip; ++i) {
        int idx = t * strip + i;
        if (idx < n) { offs[idx] = run; run += cnt[idx]; }
    }
    if (t == 1023) offs[n] = part[1023];
}

__global__ void fill_kernel(const int* __restrict__ dst, const int* __restrict__ offs,
                            int* __restrict__ cur, int* __restrict__ csr, int E) {
    int e = blockIdx.x * 256 + threadIdx.x;
    if (e < E) {
        int d = dst[e];
        int p = offs[d] + atomicAdd(&cur[d], 1);
        csr[p] = e;
    }
}

// ---------------- fused small reductions (wave-granular regions) ----------------
struct PrepSArgs {
    const float *W1, *W2, *W3, *q1, *q2, *q3, *k1, *k2, *k3;
    float *Wqk1, *Wqk2, *Wqk3;
    const float *le0, *le1, *le2, *le3, *e0, *e1, *e2, *e3;
    float* g;
    const float *b2, *lw2l, *lb2;
    float* bf2;
};

__device__ __forceinline__ void wqk_body(const float* W, const float* q, const float* k,
                                         float* Wqk, int cin, int ho, int i, int lane) {
    int c = i >> 2, r = i & 3;
    const float* wrow = W + ((long)r * cin + c) * ho;
    float sq0 = 0.f, sq1 = 0.f, sq2 = 0.f, sk0 = 0.f, sk1 = 0.f, sk2 = 0.f;
    for (int o = lane; o < ho; o += 64) {
        float w = wrow[o];
        sq0 += w * q[(long)o * 3 + 0];
        sq1 += w * q[(long)o * 3 + 1];
        sq2 += w * q[(long)o * 3 + 2];
        sk0 += w * k[(long)o * 3 + 0];
        sk1 += w * k[(long)o * 3 + 1];
        sk2 += w * k[(long)o * 3 + 2];
    }
    sq0 = wave_sum(sq0); sq1 = wave_sum(sq1); sq2 = wave_sum(sq2);
    sk0 = wave_sum(sk0); sk1 = wave_sum(sk1); sk2 = wave_sum(sk2);
    if (lane == 0) {
        float* w6 = Wqk + (long)c * 24 + r * 6;
        w6[0] = sq0; w6[1] = sq1; w6[2] = sq2;
        w6[3] = sk0; w6[4] = sk1; w6[5] = sk2;
    }
}

__global__ __launch_bounds__(256)
void preps_kernel(PrepSArgs a) {
    const int wid = threadIdx.x >> 6, lane = threadIdx.x & 63;
    int w = blockIdx.x * 4 + wid;
    if (w < 96) {
        int l = w / 24, j = w % 24;
        int d = j / 3, h = j % 3;
        const float* le = (l == 0) ? a.le0 : (l == 1 ? a.le1 : (l == 2 ? a.le2 : a.le3));
        const float* e  = (l == 0) ? a.e0  : (l == 1 ? a.e1  : (l == 2 ? a.e2  : a.e3));
        int ho = (l == 1) ? 1152 : 384;
        float s = 0.f;
        for (int o = lane; o < ho; o += 64) s += le[(long)d * ho + o] * e[(long)o * 3 + h];
        s = wave_sum(s);
        if (lane == 0) a.g[l * 24 + j] = s;
        return;
    }
    w -= 96;
    if (w < 1024) { wqk_body(a.W1, a.q1, a.k1, a.Wqk1, 256, 1152, w, lane); return; }
    w -= 1024;
    if (w < 1024) { wqk_body(a.W2, a.q2, a.k2, a.Wqk2, 256, 384, w, lane); return; }
    w -= 1024;
    if (w < 1024) { wqk_body(a.W3, a.q3, a.k3, a.Wqk3, 256, 384, w, lane); return; }
    w -= 1024;
    if (w < 256) {
        float s = 0.f;
        for (int o = lane; o < 384; o += 64) s += a.b2[o] * a.lw2l[(long)o * 256 + w];
        s = wave_sum(s);
        if (lane == 0) a.bf2[w] = s + a.lb2[w];
    }
}

// ---------------- fused weight prep + ae + qk-fold weights (regions) ----------------
struct PrepWArgs {
    const float *x, *W0, *W2, *W3, *lw0, *lw1, *lw2, *lw3, *W1;
    ushort *hbf, *Wt0, *Wt2, *Wt3, *lwT0, *lwT1, *lwT2, *lwT3, *A2;
    const float *ea, *g;
    float* aeb;
    const float *Wqk1, *Wqk3, *lb0, *lb2;
    float *qb1, *qb3;
};

__device__ __forceinline__ void trLw_body(const float* lw, ushort* lwT, int cout_in, long idx) {
    int o = (int)(idx / cout_in);
    int c = (int)(idx % cout_in);
    lwT[idx] = f2bf(lw[(long)c * 256 + o]);
}

__device__ __forceinline__ void trWT_body(const float* W, ushort* Wt, int cin, int ho,
                                          int bt, int t, float (*tile)[65]) {
    const int tpo = ho / 64;
    const int tpc = cin / 64;
    const int per_r = tpc * tpo;
    int r = bt / per_r, rem = bt % per_r;
    int c0 = (rem / tpo) * 64, o0 = (rem % tpo) * 64;
    const int ti = t >> 6, tj = t & 63;
#pragma unroll
    for (int p = 0; p < 16; ++p) {
        int c = c0 + ti + 4 * p;
        tile[ti + 4 * p][tj] = W[((long)r * cin + c) * ho + o0 + tj];
    }
    __syncthreads();
#pragma unroll
    for (int p = 0; p < 16; ++p) {
        int o = o0 + ti + 4 * p;
        Wt[((long)(r * ho + o)) * cin + c0 + tj] = f2bf(tile[tj][ti + 4 * p]);
    }
}

__global__ __launch_bounds__(256)
void prepw_kernel(PrepWArgs a, int nbCast, long nCast, int E, int nbAe) {
    __shared__ float tile[64][65];
    int b = blockIdx.x;
    const int t = threadIdx.x;
    if (b < nbCast) {
        long i = ((long)b * 256 + t) * 4;
        if (i + 4 <= nCast) {
            float4 v = *(const float4*)(a.x + i);
            ushort4 o4 = { f2bf(v.x), f2bf(v.y), f2bf(v.z), f2bf(v.w) };
            *(ushort4*)(a.hbf + i) = o4;
        }
        return;
    }
    b -= nbCast;
    if (b < 288) { trWT_body(a.W0, a.Wt0, 768, 384, b, t, tile); return; }
    b -= 288;
    if (b < 96)  { trWT_body(a.W2, a.Wt2, 256, 384, b, t, tile); return; }
    b -= 96;
    if (b < 96)  { trWT_body(a.W3, a.Wt3, 256, 384, b, t, tile); return; }
    b -= 96;
    if (b < 128)  { trLw_body(a.lw0, a.lwT0, 128, (long)b * 256 + t); return; }
    b -= 128;
    if (b < 384)  { trLw_body(a.lw1, a.lwT1, 384, (long)b * 256 + t); return; }
    b -= 384;
    if (b < 128)  { trLw_body(a.lw2, a.lwT2, 128, (long)b * 256 + t); return; }
    b -= 128;
    if (b < 128)  { trLw_body(a.lw3, a.lwT3, 128, (long)b * 256 + t); return; }
    b -= 128;
    if (b < 1728) {
        long idx = (long)b * 256 + t;
        int j = (int)(idx / 384), o = (int)(idx % 384);
        int h = j >> 10, rc = j & 1023;
        int r = rc >> 8, c = rc & 255;
        a.A2[idx] = f2bf(a.W1[((long)(r * 256 + c)) * 1152 + h * 384 + o] * (1.f / 3.f));
        return;
    }
    b -= 1728;
    if (b < nbAe) {
        int e = b * 256 + t;
        if (e >= E) return;
        float av[8];
#pragma unroll
        for (int d = 0; d < 8; ++d) av[d] = a.ea[(long)e * 8 + d];
#pragma unroll
        for (int l = 0; l < 4; ++l) {
#pragma unroll
            for (int h = 0; h < 3; ++h) {
                float s = 0.f;
#pragma unroll
                for (int d = 0; d < 8; ++d) s += av[d] * a.g[l * 24 + d * 3 + h];
                a.aeb[((size_t)l * E + e) * 3 + h] = s;
            }
        }
        return;
    }
    b -= nbAe;
    const int wid = t >> 6, lane = t & 63;
    if (b < 768) {
        int w = b * 4 + wid;
        int c = w / 24, j = w % 24;
        float s = 0.f;
        for (int o = lane; o < 256; o += 64) s += a.lw0[(long)c * 256 + o] * a.Wqk1[(long)o * 24 + j];
        s = wave_sum(s);
        if (lane == 0) a.lwT0[(256 + j) * 128 + c] = f2bf(s);
        return;
    }
    b -= 768;
    if (b < 768) {
        int w = b * 4 + wid;
        int c = w / 24, j = w % 24;
        float s = 0.f;
        for (int o = lane; o < 256; o += 64) s += a.lw2[(long)c * 256 + o] * a.Wqk3[(long)o * 24 + j];
        s = wave_sum(s);
        if (lane == 0) a.lwT2[(256 + j) * 128 + c] = f2bf(s);
        return;
    }
    b -= 768;
    if (b < 6) {
        int w = b * 4 + wid;
        if (w < 24) {
            float s = 0.f;
            for (int o = lane; o < 256; o += 64) s += a.lb0[o] * a.Wqk1[(long)o * 24 + w];
            s = wave_sum(s);
            if (lane == 0) a.qb1[w] = s;
        }
        return;
    }
    b -= 6;
    if (b < 6) {
        int w = b * 4 + wid;
        if (w < 24) {
            float s = 0.f;
            for (int o = lane; o < 256; o += 64) s += a.lb2[o] * a.Wqk3[(long)o * 24 + w];
            s = wave_sum(s);
            if (lane == 0) a.qb3[w] = s;
        }
        return;
    }
    b -= 6;
    if (b < 52) { a.lwT0[280 * 128 + b * 256 + t] = 0; return; }
    b -= 52;
    a.lwT2[280 * 128 + b * 256 + t] = 0;
}

// ---------------- qkn for layer 0 from xWb ----------------
__global__ __launch_bounds__(256)
void qkx_kernel(const ushort* __restrict__ xW, const float* __restrict__ q0,
                const float* __restrict__ k0, float* __restrict__ qkn, int N) {
    __shared__ float qv[6][384];
    const int t = threadIdx.x, wid = t >> 6, lane = t & 63;
    for (int i = t; i < 384; i += 256) {
        qv[0][i] = q0[i * 3 + 0]; qv[1][i] = q0[i * 3 + 1]; qv[2][i] = q0[i * 3 + 2];
        qv[3][i] = k0[i * 3 + 0]; qv[4][i] = k0[i * 3 + 1]; qv[5][i] = k0[i * 3 + 2];
    }
    __syncthreads();
    const int n = blockIdx.x * 4 + wid;
    if (n >= N) return;
    const ushort* row = xW + (long)n * 1536;
    float acc[24];
#pragma unroll
    for (int j = 0; j < 24; ++j) acc[j] = 0.f;
#pragma unroll
    for (int r = 0; r < 4; ++r) {
#pragma unroll
        for (int jj = 0; jj < 3; ++jj) {
            int o = jj * 128 + lane * 2;
            uint v = *(const uint*)(row + r * 384 + o);
            float x0 = bf2f((ushort)(v & 0xffffu));
            float x1 = bf2f((ushort)(v >> 16));
#pragma unroll
            for (int t6 = 0; t6 < 6; ++t6)
                acc[r * 6 + t6] += x0 * qv[t6][o] + x1 * qv[t6][o + 1];
        }
    }
#pragma unroll
    for (int j = 0; j < 24; ++j) {
        float v = wave_sum(acc[j]);
        if (lane == 0) qkn[(long)n * 24 + j] = v;
    }
}

// ---------------- bf16 MFMA GEMM (2-phase double-buffered) ----------------
template<int OUT_BF16, int DUAL, int PARTIAL, int QK>
__global__ __launch_bounds__(256, 5)
void gemm_bf16(const ushort* __restrict__ A, const ushort* __restrict__ Bt,
               void* __restrict__ Cp, ushort* __restrict__ C2,
               const float* __restrict__ bias,
               int M, int K, int ldc, int nbn, int nwg, int nbase, int Ks,
               float* __restrict__ qkn, const float* __restrict__ qb, int qkcol) {
    __shared__ ushort lA[2][128 * 32];
    __shared__ ushort lB[2][128 * 32];
    const int t = threadIdx.x;
    const int lane = t & 63;
    const int wid = t >> 6;

    int b = blockIdx.x;
    int q8 = nwg >> 3, r8 = nwg & 7;
    int xcd = b & 7, loc = b >> 3;
    int tt = (xcd < r8 ? xcd * (q8 + 1) : r8 * (q8 + 1) + (xcd - r8) * q8) + loc;
    const int slice = tt / nbase;
    const int tile = tt % nbase;
    const int kbase = slice * Ks;
    const int bm = (tile / nbn) * 128;
    const int bn = (tile % nbn) * 128;

    const int wr = (wid >> 1) * 64;
    const int wc = (wid & 1) * 64;

    f32x4 acc[4][4];
#pragma unroll
    for (int m = 0; m < 4; ++m)
#pragma unroll
        for (int nn = 0; nn < 4; ++nn) acc[m][nn] = (f32x4){0.f, 0.f, 0.f, 0.f};

    const int sr = t >> 2;
    const int sk = (((t & 3) ^ ((t >> 3) & 3)) * 8);
    long ar0 = bm + sr;      if (ar0 > M - 1) ar0 = M - 1;
    long ar1 = bm + sr + 64; if (ar1 > M - 1) ar1 = M - 1;
    const ushort* gA0 = A + ar0 * K + sk + kbase;
    const ushort* gA1 = A + ar1 * K + sk + kbase;
    const ushort* gB0 = Bt + (long)(bn + sr) * K + sk + kbase;
    const ushort* gB1 = Bt + (long)(bn + sr + 64) * K + sk + kbase;

    const int frow = lane & 15;
    const int pc8 = (((lane >> 4) ^ ((lane >> 1) & 3)) * 8);

    GLD_LDS(gA0, &lA[0][t * 8]);
    GLD_LDS(gA1, &lA[0][t * 8 + 64 * 32]);
    GLD_LDS(gB0, &lB[0][t * 8]);
    GLD_LDS(gB1, &lB[0][t * 8 + 64 * 32]);
    __syncthreads();

    int cur = 0;
    for (int k0 = 0; k0 < Ks; k0 += 32) {
        if (k0 + 32 < Ks) {
            int nb = cur ^ 1, kn = k0 + 32;
            GLD_LDS(gA0 + kn, &lA[nb][t * 8]);
            GLD_LDS(gA1 + kn, &lA[nb][t * 8 + 64 * 32]);
            GLD_LDS(gB0 + kn, &lB[nb][t * 8]);
            GLD_LDS(gB1 + kn, &lB[nb][t * 8 + 64 * 32]);
        }
        bf16x8 af[4], bff[4];
#pragma unroll
        for (int m = 0; m < 4; ++m)
            af[m] = *(const bf16x8*)&lA[cur][(wr + m * 16 + frow) * 32 + pc8];
#pragma unroll
        for (int nn = 0; nn < 4; ++nn)
            bff[nn] = *(const bf16x8*)&lB[cur][(wc + nn * 16 + frow) * 32 + pc8];
#pragma unroll
        for (int m = 0; m < 4; ++m)
#pragma unroll
            for (int nn = 0; nn < 4; ++nn)
                acc[m][nn] = __builtin_amdgcn_mfma_f32_16x16x32_bf16(af[m], bff[nn], acc[m][nn], 0, 0, 0);
        __syncthreads();
        cur ^= 1;
    }

    const int crow = (lane >> 4) * 4;
    const int ccol = lane & 15;
#pragma unroll
    for (int m = 0; m < 4; ++m) {
#pragma unroll
        for (int nn = 0; nn < 4; ++nn) {
            int col = bn + wc + nn * 16 + ccol;
#pragma unroll
            for (int r = 0; r < 4; ++r) {
                int row = bm + wr + m * 16 + crow + r;
                if (row < M) {
                    float v = acc[m][nn][r];
                    if (QK && col >= qkcol) {
                        int qc = col - qkcol;
                        if (qc < 24) qkn[(long)row * 24 + qc] = v + (qb ? qb[qc] : 0.f);
                    } else {
                        if (!PARTIAL && bias) v += bias[col];
                        if (PARTIAL) {
                            ((float*)Cp)[(size_t)slice * M * ldc + (long)row * ldc + col] = v;
                        } else {
                            if (OUT_BF16) ((ushort*)Cp)[(long)row * ldc + col] = f2bf(v);
                            else          ((float*)Cp)[(long)row * ldc + col] = v;
                            if (DUAL)     C2[(long)row * ldc + col] = f2bf(v);
                        }
                    }
                }
            }
        }
    }
}

// ---------------- split-K reduce + fused qk for layer 2 ----------------
__global__ __launch_bounds__(256)
void reduce3qk_kernel(const float* __restrict__ P, const float* __restrict__ bf2,
                      const float* __restrict__ Wqk2,
                      float* __restrict__ outf, ushort* __restrict__ outb,
                      float* __restrict__ qkn, int M) {
    const int wid = threadIdx.x >> 6, lane = threadIdx.x & 63;
    const int n = blockIdx.x * 4 + wid;
    if (n >= M) return;
    long off = (long)n * 256 + lane * 4;
    const long stride = (long)M * 256;
    float4 a = *(const float4*)(P + off);
    float4 b = *(const float4*)(P + stride + off);
    float4 c = *(const float4*)(P + 2 * stride + off);
    float4 bs = *(const float4*)(bf2 + lane * 4);
    float rr[4] = { a.x + b.x + c.x + bs.x, a.y + b.y + c.y + bs.y,
                    a.z + b.z + c.z + bs.z, a.w + b.w + c.w + bs.w };
    float4 r4 = { rr[0], rr[1], rr[2], rr[3] };
    *(float4*)(outf + off) = r4;
    ushort4 o4 = { f2bf(rr[0]), f2bf(rr[1]), f2bf(rr[2]), f2bf(rr[3]) };
    *(ushort4*)(outb + off) = o4;
    float acc[24];
#pragma unroll
    for (int j = 0; j < 24; ++j) acc[j] = 0.f;
#pragma unroll
    for (int i = 0; i < 4; ++i) {
        const float* wr = Wqk2 + (long)(lane * 4 + i) * 24;
        float hv = rr[i];
#pragma unroll
        for (int j = 0; j < 24; ++j) acc[j] += hv * wr[j];
    }
#pragma unroll
    for (int j = 0; j < 24; ++j) {
        float v = wave_sum(acc[j]);
        if (lane == 0) qkn[(long)n * 24 + j] = v;
    }
}

// ================= attention (wave-per-node, 4-slot pipelined gather) =================
__global__ __launch_bounds__(256)
void attn_kernel(const float* __restrict__ qkn, const ushort* __restrict__ xW,
                 const float* __restrict__ ae, const int* __restrict__ offs,
                 const int* __restrict__ csr, const int* __restrict__ srcv,
                 const int* __restrict__ etv, const float* __restrict__ bias,
                 ushort* __restrict__ out, int N, int ldx) {
    __shared__ float4 pk_sh[4][64];
    __shared__ float red[4][384];
    const int wid = threadIdx.x >> 6, lane = threadIdx.x & 63;
    const int n = blockIdx.x * 4 + wid;
    if (n >= N) return;
    const int e0 = offs[n];
    const int deg = offs[n + 1] - e0;
    const float* qd = qkn + (long)n * 24;

    float m0 = -1e30f, m1 = -1e30f, m2 = -1e30f;
    for (int base = 0; base < deg; base += 64) {
        int idx = base + lane;
        if (idx < deg) {
            int eid = csr[e0 + idx];
            int s_ = srcv[eid], t_ = etv[eid];
            const float* qs = qkn + (long)s_ * 24 + t_ * 6;
            const float* a3 = ae + (long)eid * 3;
            float v0 = qd[t_ * 6 + 0] + qs[3] + a3[0];
            float v1 = qd[t_ * 6 + 1] + qs[4] + a3[1];
            float v2 = qd[t_ * 6 + 2] + qs[5] + a3[2];
            v0 = v0 > 0.f ? v0 : 0.2f * v0;
            v1 = v1 > 0.f ? v1 : 0.2f * v1;
            v2 = v2 > 0.f ? v2 : 0.2f * v2;
            m0 = fmaxf(m0, v0); m1 = fmaxf(m1, v1); m2 = fmaxf(m2, v2);
        }
    }
    m0 = wave_max(m0); m1 = wave_max(m1); m2 = wave_max(m2);

    float acc[6] = {0.f, 0.f, 0.f, 0.f, 0.f, 0.f};
    float ps0 = 0.f, ps1 = 0.f, ps2 = 0.f;

    for (int base = 0; base < deg; base += 64) {
        int cnt2 = deg - base; if (cnt2 > 64) cnt2 = 64;
        if (lane < cnt2) {
            int eid = csr[e0 + base + lane];
            int s_ = srcv[eid], t_ = etv[eid];
            const float* qs = qkn + (long)s_ * 24 + t_ * 6;
            const float* a3 = ae + (long)eid * 3;
            float v0 = qd[t_ * 6 + 0] + qs[3] + a3[0];
            float v1 = qd[t_ * 6 + 1] + qs[4] + a3[1];
            float v2 = qd[t_ * 6 + 2] + qs[5] + a3[2];
            v0 = v0 > 0.f ? v0 : 0.2f * v0;
            v1 = v1 > 0.f ? v1 : 0.2f * v1;
            v2 = v2 > 0.f ? v2 : 0.2f * v2;
            float p0 = __expf(v0 - m0), p1 = __expf(v1 - m1), p2 = __expf(v2 - m2);
            pk_sh[wid][lane] = make_float4(p0, p1, p2, __int_as_float((s_ << 2) | t_));
            ps0 += p0; ps1 += p1; ps2 += p2;
        }
        wave_sync();
        float4 pk0 = {0,0,0,0}, pk1 = {0,0,0,0}, pk2 = {0,0,0,0}, pk3 = {0,0,0,0};
        uint a0 = 0, b0 = 0, c0 = 0, a1 = 0, b1 = 0, c1 = 0;
        uint a2 = 0, b2 = 0, c2 = 0, a3 = 0, b3 = 0, c3 = 0;
#define LDE(S, J) { pk##S = pk_sh[wid][J]; int pk_ = __float_as_int(pk##S.w); \
    const uint* xr = (const uint*)(xW + (long)(pk_ >> 2) * ldx + (pk_ & 3) * 384); \
    a##S = xr[lane]; b##S = xr[lane + 64]; c##S = xr[lane + 128]; }
#define ACCE(S) { \
    acc[0] += pk##S.x * bf2f((ushort)(a##S & 0xffffu)); \
    acc[1] += pk##S.x * bf2f((ushort)(a##S >> 16)); \
    acc[2] += pk##S.y * bf2f((ushort)(b##S & 0xffffu)); \
    acc[3] += pk##S.y * bf2f((ushort)(b##S >> 16)); \
    acc[4] += pk##S.z * bf2f((ushort)(c##S & 0xffffu)); \
    acc[5] += pk##S.z * bf2f((ushort)(c##S >> 16)); }
        if (0 < cnt2) LDE(0, 0);
        if (1 < cnt2) LDE(1, 1);
        if (2 < cnt2) LDE(2, 2);
        if (3 < cnt2) LDE(3, 3);
        for (int j = 0; j < cnt2; j += 4) {
            { ACCE(0); if (j + 4 < cnt2) LDE(0, j + 4); }
            if (j + 1 < cnt2) { ACCE(1); if (j + 5 < cnt2) LDE(1, j + 5); }
            if (j + 2 < cnt2) { ACCE(2); if (j + 6 < cnt2) LDE(2, j + 6); }
            if (j + 3 < cnt2) { ACCE(3); if (j + 7 < cnt2) LDE(3, j + 7); }
        }
#undef LDE
#undef ACCE
        wave_sync();
    }
    ps0 = wave_sum(ps0); ps1 = wave_sum(ps1); ps2 = wave_sum(ps2);
    float i0 = 1.f / fmaxf(ps0, 1e-16f);
    float i1 = 1.f / fmaxf(ps1, 1e-16f);
    float i2 = 1.f / fmaxf(ps2, 1e-16f);
    red[wid][2 * lane]           = acc[0] * i0;
    red[wid][2 * lane + 1]       = acc[1] * i0;
    red[wid][128 + 2 * lane]     = acc[2] * i1;
    red[wid][128 + 2 * lane + 1] = acc[3] * i1;
    red[wid][256 + 2 * lane]     = acc[4] * i2;
    red[wid][256 + 2 * lane + 1] = acc[5] * i2;
    wave_sync();
    for (int o = lane; o < 128; o += 64) {
        float v = (red[wid][o] + red[wid][128 + o] + red[wid][256 + o]) * (1.f / 3.f) + bias[o];
        out[(long)n * 128 + o] = f2bf(v);
    }
}

// layer 2: Z-accumulation, channel-split: 2 waves per node (half = 128 channels each)
__global__ __launch_bounds__(256)
void attn2_kernel(const float* __restrict__ qkn, const ushort* __restrict__ hbf,
                  const float* __restrict__ ae, const int* __restrict__ offs,
                  const int* __restrict__ csr, const int* __restrict__ srcv,
                  const int* __restrict__ etv, ushort* __restrict__ Z, int N) {
    __shared__ float4 pk_sh[4][64];
    const int wid = threadIdx.x >> 6, lane = threadIdx.x & 63;
    const int n = blockIdx.x * 2 + (wid >> 1);
    const int half = wid & 1;
    if (n >= N) return;
    const int e0 = offs[n];
    const int deg = offs[n + 1] - e0;
    const float* qd = qkn + (long)n * 24;

    float m0 = -1e30f, m1 = -1e30f, m2 = -1e30f;
    for (int base = 0; base < deg; base += 64) {
        int idx = base + lane;
        if (idx < deg) {
            int eid = csr[e0 + idx];
            int s_ = srcv[eid], t_ = etv[eid];
            const float* qs = qkn + (long)s_ * 24 + t_ * 6;
            const float* a3 = ae + (long)eid * 3;
            float v0 = qd[t_ * 6 + 0] + qs[3] + a3[0];
            float v1 = qd[t_ * 6 + 1] + qs[4] + a3[1];
            float v2 = qd[t_ * 6 + 2] + qs[5] + a3[2];
            v0 = v0 > 0.f ? v0 : 0.2f * v0;
            v1 = v1 > 0.f ? v1 : 0.2f * v1;
            v2 = v2 > 0.f ? v2 : 0.2f * v2;
            m0 = fmaxf(m0, v0); m1 = fmaxf(m1, v1); m2 = fmaxf(m2, v2);
        }
    }
    m0 = wave_max(m0); m1 = wave_max(m1); m2 = wave_max(m2);

    float acc[24];   // [h][r][2]
#pragma unroll
    for (int i = 0; i < 24; ++i) acc[i] = 0.f;
    float ps0 = 0.f, ps1 = 0.f, ps2 = 0.f;

    const ushort* hb = hbf + half * 128 + lane * 2;

    for (int base = 0; base < deg; base += 64) {
        int cnt2 = deg - base; if (cnt2 > 64) cnt2 = 64;
        if (lane < cnt2) {
            int eid = csr[e0 + base + lane];
            int s_ = srcv[eid], t_ = etv[eid];
            const float* qs = qkn + (long)s_ * 24 + t_ * 6;
            const float* a3 = ae + (long)eid * 3;
            float v0 = qd[t_ * 6 + 0] + qs[3] + a3[0];
            float v1 = qd[t_ * 6 + 1] + qs[4] + a3[1];
            float v2 = qd[t_ * 6 + 2] + qs[5] + a3[2];
            v0 = v0 > 0.f ? v0 : 0.2f * v0;
            v1 = v1 > 0.f ? v1 : 0.2f * v1;
            v2 = v2 > 0.f ? v2 : 0.2f * v2;
            float p0 = __expf(v0 - m0), p1 = __expf(v1 - m1), p2 = __expf(v2 - m2);
            pk_sh[wid][lane] = make_float4(p0, p1, p2, __int_as_float((s_ << 2) | t_));
            ps0 += p0; ps1 += p1; ps2 += p2;
        }
        wave_sync();
        float4 pk0 = {0,0,0,0}, pk1 = {0,0,0,0}, pk2 = {0,0,0,0}, pk3 = {0,0,0,0};
        uint v0_ = 0, v1_ = 0, v2_ = 0, v3_ = 0;
#define LDE2(S, J) { pk##S = pk_sh[wid][J]; \
    v##S##_ = *(const uint*)(hb + ((long)(__float_as_int(pk##S.w) >> 2)) * 256); }
#define UPDR(R) { \
    acc[(R)*2+0] += px * x0; acc[(R)*2+1] += px * x1; \
    acc[8+(R)*2+0] += py * x0; acc[8+(R)*2+1] += py * x1; \
    acc[16+(R)*2+0] += pz * x0; acc[16+(R)*2+1] += pz * x1; }
#define ACC2(S) { int r_ = __float_as_int(pk##S.w) & 3; \
    float x0 = bf2f((ushort)(v##S##_ & 0xffffu)), x1 = bf2f((ushort)(v##S##_ >> 16)); \
    float px = pk##S.x, py = pk##S.y, pz = pk##S.z; \
    if (r_ == 0) UPDR(0) else if (r_ == 1) UPDR(1) else if (r_ == 2) UPDR(2) else UPDR(3) }
        if (0 < cnt2) LDE2(0, 0);
        if (1 < cnt2) LDE2(1, 1);
        if (2 < cnt2) LDE2(2, 2);
        if (3 < cnt2) LDE2(3, 3);
        for (int j = 0; j < cnt2; j += 4) {
            { ACC2(0); if (j + 4 < cnt2) LDE2(0, j + 4); }
            if (j + 1 < cnt2) { ACC2(1); if (j + 5 < cnt2) LDE2(1, j + 5); }
            if (j + 2 < cnt2) { ACC2(2); if (j + 6 < cnt2) LDE2(2, j + 6); }
            if (j + 3 < cnt2) { ACC2(3); if (j + 7 < cnt2) LDE2(3, j + 7); }
        }
#undef LDE2
#undef UPDR
#undef ACC2
        wave_sync();
    }
    ps0 = wave_sum(ps0); ps1 = wave_sum(ps1); ps2 = wave_sum(ps2);
    float inv0 = 1.f / fmaxf(ps0, 1e-16f);
    float inv1 = 1.f / fmaxf(ps1, 1e-16f);
    float inv2 = 1.f / fmaxf(ps2, 1e-16f);
    ushort* zr = Z + (long)n * 3072 + half * 128 + lane * 2;
#pragma unroll
    for (int h = 0; h < 3; ++h) {
        float iv = (h == 0) ? inv0 : (h == 1 ? inv1 : inv2);
#pragma unroll
        for (int r = 0; r < 4; ++r) {
            ushort2 o2 = { f2bf(acc[h * 8 + r * 2] * iv), f2bf(acc[h * 8 + r * 2 + 1] * iv) };
            *(ushort2*)(zr + h * 1024 + r * 256) = o2;
        }
    }
}

// ---------------- final: hole-node softmax ----------------
__global__ void softmax_kernel(const float* __restrict__ h, const int* __restrict__ hole,
                               float* __restrict__ out, int B) {
    int b = blockIdx.x;
    int t = threadIdx.x;
    int lane = t & 63, wid = t >> 6;
    __shared__ float sm[4];
    __shared__ float ss[4];
    int row = hole[b];
    float v = h[(long)row * 256 + t];
    float m = v;
#pragma unroll
    for (int d = 32; d >= 1; d >>= 1) m = fmaxf(m, __shfl_xor(m, d));
    if (lane == 0) sm[wid] = m;
    __syncthreads();
    m = fmaxf(fmaxf(sm[0], sm[1]), fmaxf(sm[2], sm[3]));
    float ex = __expf(v - m);
    float s = ex;
#pragma unroll
    for (int d = 32; d >= 1; d >>= 1) s += __shfl_xor(s, d);
    if (lane == 0) ss[wid] = s;
    __syncthreads();
    s = ss[0] + ss[1] + ss[2] + ss[3];
    out[(long)b * 256 + t] = ex / s;
}

// ---------------- host ----------------
extern "C" void kernel_launch(void* const* d_in, const int* in_sizes, int n_in,
                              void* d_out, int out_size, void* d_ws, size_t ws_size,
                              hipStream_t stream) {
    const float* x   = (const float*)d_in[0];
    const int*   ei  = (const int*)d_in[1];
    const int*   ety = (const int*)d_in[2];
    const float* ea  = (const float*)d_in[3];
    const int*   bat = (const int*)d_in[4];

    const int N = in_sizes[0] / 768;
    const int E = in_sizes[2];
    const int B = out_size / 256;

    static const int CIN[4]  = {768, 256, 256, 256};
    static const int COUT[4] = {128, 384, 128, 128};
    static const int NCC[4]  = {1536, 4608, 1536, 1536};

    const float *Wp[4], *qp[4], *kp[4], *lep[4], *ep[4], *bp[4], *lwp[4], *lbp[4];
    for (int l = 0; l < 4; ++l) {
        Wp[l]  = (const float*)d_in[5 + 6 * l];
        qp[l]  = (const float*)d_in[6 + 6 * l];
        kp[l]  = (const float*)d_in[7 + 6 * l];
        lep[l] = (const float*)d_in[8 + 6 * l];
        ep[l]  = (const float*)d_in[9 + 6 * l];
        bp[l]  = (const float*)d_in[10 + 6 * l];
        lwp[l] = (const float*)d_in[29 + 2 * l];
        lbp[l] = (const float*)d_in[30 + 2 * l];
    }

    char* ws = (char*)d_ws;
    size_t pos = 0;
    auto carve = [&](size_t bytes) -> char* {
        char* r = ws + pos;
        pos += (bytes + 255) & ~(size_t)255;
        return r;
    };
    ushort *Wt[4], *lwT[4];
    float* Wqk[4];
    for (int l = 0; l < 4; ++l) Wt[l]  = (ushort*)carve(l == 1 ? 0 : (size_t)2 * NCC[l] * CIN[l]);
    for (int l = 0; l < 4; ++l) lwT[l] = (ushort*)carve((size_t)2 * 384 * COUT[l]);
    for (int l = 0; l < 4; ++l) Wqk[l] = (float*)carve((size_t)4 * 24 * CIN[l]);
    float*  gbuf  = (float*)carve(4 * 24 * 4);
    float*  aeb   = (float*)carve((size_t)4 * E * 3 * 4);
    float*  qkn   = (float*)carve((size_t)N * 24 * 4);
    float*  qb1   = (float*)carve(24 * 4);
    float*  qb3   = (float*)carve(24 * 4);
    ushort* hbf   = (ushort*)carve((size_t)N * 768 * 2);
    ushort* xWb   = (ushort*)carve((size_t)N * 1536 * 2);   // also split-K fp32 partials
    ushort* Zb    = (ushort*)carve((size_t)N * 3072 * 2);
    ushort* A2    = (ushort*)carve((size_t)3072 * 384 * 2);
    ushort* W2T   = (ushort*)carve((size_t)256 * 3072 * 2);
    float*  bf2   = (float*)carve(256 * 4);
    ushort* convbf= (ushort*)carve((size_t)N * 384 * 2);
    float*  hbuf  = (float*)carve((size_t)N * 256 * 4);
    int* cnt  = (int*)carve((size_t)N * 4);
    int* cur  = (int*)carve((size_t)N * 4);
    int* offs = (int*)carve((size_t)(N + 1) * 4);
    int* csr  = (int*)carve((size_t)E * 4);
    int* hole = (int*)carve((size_t)B * 4);

    hipMemsetAsync(cnt, 0, (size_t)((char*)cur - (char*)cnt) + (size_t)N * 4, stream);
    hipMemsetAsync(hole, 0x7f, (size_t)B * 4, stream);

    const int* dst = ei + E;
    int nbEH = ((E > N ? E : N) + 255) / 256;
    deg_hole_kernel<<<nbEH, 256, 0, stream>>>(dst, cnt, bat, hole, E, N);
    scan_kernel<<<1, 1024, 0, stream>>>(cnt, offs, N);
    fill_kernel<<<(E + 255) / 256, 256, 0, stream>>>(dst, offs, cur, csr, E);

    PrepSArgs psa = { Wp[1], Wp[2], Wp[3], qp[1], qp[2], qp[3],
                      kp[1], kp[2], kp[3], Wqk[1], Wqk[2], Wqk[3],
                      lep[0], lep[1], lep[2], lep[3], ep[0], ep[1], ep[2], ep[3],
                      gbuf, bp[1], lwp[1], lbp[1], bf2 };
    preps_kernel<<<(3424 + 3) / 4, 256, 0, stream>>>(psa);

    long nCast = (long)N * 768;
    int nbCast = (int)((nCast / 4 + 255) / 256);
    int nbAe = (E + 255) / 256;
    PrepWArgs pw = { x, Wp[0], Wp[2], Wp[3], lwp[0], lwp[1], lwp[2], lwp[3], Wp[1],
                     hbf, Wt[0], Wt[2], Wt[3], lwT[0], lwT[1], lwT[2], lwT[3], A2,
                     ea, gbuf, aeb, Wqk[1], Wqk[3], lbp[0], lbp[2], qb1, qb3 };
    prepw_kernel<<<nbCast + nbAe + 4628, 256, 0, stream>>>(pw, nbCast, nCast, E, nbAe);

    gemm_bf16<1, 0, 0, 0><<<48, 256, 0, stream>>>(lwT[1], A2, (void*)W2T, nullptr, nullptr,
                                                  256, 384, 3072, 24, 48, 48, 384,
                                                  nullptr, nullptr, 0);

    const int nbm = (N + 127) / 128;
    for (int l = 0; l < 4; ++l) {
        if (l == 1) {
            attn2_kernel<<<(N + 1) / 2, 256, 0, stream>>>(qkn, hbf, aeb + (size_t)l * E * 3,
                                                          offs, csr, ei, ety, Zb, N);
            int nbase = nbm * 2, nwgS = nbase * 3;
            gemm_bf16<0, 0, 1, 0><<<nwgS, 256, 0, stream>>>(Zb, W2T, (void*)xWb, nullptr, nullptr,
                                                            N, 3072, 256, 2, nwgS, nbase, 1024,
                                                            nullptr, nullptr, 0);
            reduce3qk_kernel<<<(N + 3) / 4, 256, 0, stream>>>((const float*)xWb, bf2, Wqk[2],
                                                              hbuf, hbf, qkn, N);
        } else {
            int nbn1 = NCC[l] / 128, nwg1 = nbm * nbn1;
            gemm_bf16<1, 0, 0, 0><<<nwg1, 256, 0, stream>>>(hbf, Wt[l], (void*)xWb, nullptr,
                                                            nullptr, N, CIN[l], NCC[l], nbn1,
                                                            nwg1, nwg1, CIN[l],
                                                            nullptr, nullptr, 0);
            if (l == 0)
                qkx_kernel<<<(N + 3) / 4, 256, 0, stream>>>(xWb, qp[0], kp[0], qkn, N);
            attn_kernel<<<(N + 3) / 4, 256, 0, stream>>>(qkn, xWb, aeb + (size_t)l * E * 3,
                                                         offs, csr, ei, ety, bp[l], convbf, N, 1536);
            if (l == 3) {
                int nwg2 = nbm * 2;
                gemm_bf16<0, 0, 0, 0><<<nwg2, 256, 0, stream>>>(convbf, lwT[3], (void*)hbuf, nullptr,
                                                                lbp[3], N, 128, 256, 2, nwg2, nwg2, 128,
                                                                nullptr, nullptr, 0);
            } else {
                float* qbp = (l == 0) ? qb1 : qb3;
                int nwg2 = nbm * 3;
                gemm_bf16<0, 1, 0, 1><<<nwg2, 256, 0, stream>>>(convbf, lwT[l], (void*)hbuf, hbf,
                                                                lbp[l], N, 128, 256, 3, nwg2, nwg2, 128,
                                                                qkn, qbp, 256);
            }
        }
    }
    softmax_kernel<<<B, 256, 0, stream>>>(hbuf, hole, (float*)d_out, B);
}

// Round 18
// 464.115 us; speedup vs baseline: 1.8941x; 1.8941x over previous
//
#include <hip/hip_runtime.h>

typedef unsigned int uint;
typedef unsigned short ushort;
typedef __attribute__((ext_vector_type(8))) short bf16x8;
typedef __attribute__((ext_vector_type(4))) float f32x4;

#define GLD_LDS(g, l) __builtin_amdgcn_global_load_lds( \
    (const __attribute__((address_space(1))) void*)(g), \
    (__attribute__((address_space(3))) void*)(l), 16, 0, 0)

__device__ __forceinline__ ushort f2bf(float f) {
    uint u = __builtin_bit_cast(uint, f);
    u += 0x7fffu + ((u >> 16) & 1u);
    return (ushort)(u >> 16);
}
__device__ __forceinline__ float bf2f(ushort s) {
    uint u = ((uint)s) << 16;
    return __builtin_bit_cast(float, u);
}
__device__ __forceinline__ void wave_sync() {
    asm volatile("s_waitcnt lgkmcnt(0)" ::: "memory");
}
__device__ __forceinline__ float wave_max(float v) {
#pragma unroll
    for (int d = 32; d >= 1; d >>= 1) v = fmaxf(v, __shfl_xor(v, d));
    return v;
}
__device__ __forceinline__ float wave_sum(float v) {
#pragma unroll
    for (int d = 32; d >= 1; d >>= 1) v += __shfl_xor(v, d);
    return v;
}

// ---------------- CSR build ----------------
__global__ void deg_hole_kernel(const int* __restrict__ dst, int* __restrict__ cnt,
                                const int* __restrict__ bat, int* __restrict__ hole,
                                int E, int N) {
    int e = blockIdx.x * 256 + threadIdx.x;
    if (e < E) atomicAdd(&cnt[dst[e]], 1);
    if (e < N) atomicMin(&hole[bat[e]], e);
}

__global__ void scan_kernel(const int* __restrict__ cnt, int* __restrict__ offs, int n) {
    __shared__ int part[1024];
    const int t = threadIdx.x;
    const int strip = (n + 1023) / 1024;
    int s = 0;
    for (int i = 0; i < strip; ++i) {
        int idx = t * strip + i;
        if (idx < n) s += cnt[idx];
    }
    part[t] = s;
    __syncthreads();
    for (int d = 1; d < 1024; d <<= 1) {
        int v = (t >= d) ? part[t - d] : 0;
        __syncthreads();
        part[t] += v;
        __syncthreads();
    }
    int run = (t == 0) ? 0 : part[t - 1];
    for (int i = 0; i < strip; ++i) {
        int idx = t * strip + i;
        if (idx < n) { offs[idx] = run; run += cnt[idx]; }
    }
    if (t == 1023) offs[n] = part[1023];
}

__global__ void fill_kernel(const int* __restrict__ dst, const int* __restrict__ offs,
                            int* __restrict__ cur, int* __restrict__ csr, int E) {
    int e = blockIdx.x * 256 + threadIdx.x;
    if (e < E) {
        int d = dst[e];
        int p = offs[d] + atomicAdd(&cur[d], 1);
        csr[p] = e;
    }
}

// ---------------- fused small reductions (wave-granular regions) ----------------
struct PrepSArgs {
    const float *W1, *W2, *W3, *q1, *q2, *q3, *k1, *k2, *k3;
    float *Wqk1, *Wqk2, *Wqk3;
    const float *le0, *le1, *le2, *le3, *e0, *e1, *e2, *e3;
    float* g;
    const float *b2, *lw2l, *lb2;
    float* bf2;
};

__device__ __forceinline__ void wqk_body(const float* W, const float* q, const float* k,
                                         float* Wqk, int cin, int ho, int i, int lane) {
    int c = i >> 2, r = i & 3;
    const float* wrow = W + ((long)r * cin + c) * ho;
    float sq0 = 0.f, sq1 = 0.f, sq2 = 0.f, sk0 = 0.f, sk1 = 0.f, sk2 = 0.f;
    for (int o = lane; o < ho; o += 64) {
        float w = wrow[o];
        sq0 += w * q[(long)o * 3 + 0];
        sq1 += w * q[(long)o * 3 + 1];
        sq2 += w * q[(long)o * 3 + 2];
        sk0 += w * k[(long)o * 3 + 0];
        sk1 += w * k[(long)o * 3 + 1];
        sk2 += w * k[(long)o * 3 + 2];
    }
    sq0 = wave_sum(sq0); sq1 = wave_sum(sq1); sq2 = wave_sum(sq2);
    sk0 = wave_sum(sk0); sk1 = wave_sum(sk1); sk2 = wave_sum(sk2);
    if (lane == 0) {
        float* w6 = Wqk + (long)c * 24 + r * 6;
        w6[0] = sq0; w6[1] = sq1; w6[2] = sq2;
        w6[3] = sk0; w6[4] = sk1; w6[5] = sk2;
    }
}

__global__ __launch_bounds__(256)
void preps_kernel(PrepSArgs a) {
    const int wid = threadIdx.x >> 6, lane = threadIdx.x & 63;
    int w = blockIdx.x * 4 + wid;
    if (w < 96) {
        int l = w / 24, j = w % 24;
        int d = j / 3, h = j % 3;
        const float* le = (l == 0) ? a.le0 : (l == 1 ? a.le1 : (l == 2 ? a.le2 : a.le3));
        const float* e  = (l == 0) ? a.e0  : (l == 1 ? a.e1  : (l == 2 ? a.e2  : a.e3));
        int ho = (l == 1) ? 1152 : 384;
        float s = 0.f;
        for (int o = lane; o < ho; o += 64) s += le[(long)d * ho + o] * e[(long)o * 3 + h];
        s = wave_sum(s);
        if (lane == 0) a.g[l * 24 + j] = s;
        return;
    }
    w -= 96;
    if (w < 1024) { wqk_body(a.W1, a.q1, a.k1, a.Wqk1, 256, 1152, w, lane); return; }
    w -= 1024;
    if (w < 1024) { wqk_body(a.W2, a.q2, a.k2, a.Wqk2, 256, 384, w, lane); return; }
    w -= 1024;
    if (w < 1024) { wqk_body(a.W3, a.q3, a.k3, a.Wqk3, 256, 384, w, lane); return; }
    w -= 1024;
    if (w < 256) {
        float s = 0.f;
        for (int o = lane; o < 384; o += 64) s += a.b2[o] * a.lw2l[(long)o * 256 + w];
        s = wave_sum(s);
        if (lane == 0) a.bf2[w] = s + a.lb2[w];
    }
}

// ---------------- fused weight prep + ae + qk-fold weights (regions) ----------------
struct PrepWArgs {
    const float *x, *W0, *W2, *W3, *lw0, *lw1, *lw2, *lw3, *W1;
    ushort *hbf, *Wt0, *Wt2, *Wt3, *lwT0, *lwT1, *lwT2, *lwT3, *A2;
    const float *ea, *g;
    float* aeb;
    const float *Wqk1, *Wqk3, *lb0, *lb2;
    float *qb1, *qb3;
};

__device__ __forceinline__ void trLw_body(const float* lw, ushort* lwT, int cout_in, long idx) {
    int o = (int)(idx / cout_in);
    int c = (int)(idx % cout_in);
    lwT[idx] = f2bf(lw[(long)c * 256 + o]);
}

__device__ __forceinline__ void trWT_body(const float* W, ushort* Wt, int cin, int ho,
                                          int bt, int t, float (*tile)[65]) {
    const int tpo = ho / 64;
    const int tpc = cin / 64;
    const int per_r = tpc * tpo;
    int r = bt / per_r, rem = bt % per_r;
    int c0 = (rem / tpo) * 64, o0 = (rem % tpo) * 64;
    const int ti = t >> 6, tj = t & 63;
#pragma unroll
    for (int p = 0; p < 16; ++p) {
        int c = c0 + ti + 4 * p;
        tile[ti + 4 * p][tj] = W[((long)r * cin + c) * ho + o0 + tj];
    }
    __syncthreads();
#pragma unroll
    for (int p = 0; p < 16; ++p) {
        int o = o0 + ti + 4 * p;
        Wt[((long)(r * ho + o)) * cin + c0 + tj] = f2bf(tile[tj][ti + 4 * p]);
    }
}

__global__ __launch_bounds__(256)
void prepw_kernel(PrepWArgs a, int nbCast, long nCast, int E, int nbAe) {
    __shared__ float tile[64][65];
    int b = blockIdx.x;
    const int t = threadIdx.x;
    if (b < nbCast) {
        long i = ((long)b * 256 + t) * 4;
        if (i + 4 <= nCast) {
            float4 v = *(const float4*)(a.x + i);
            ushort4 o4 = { f2bf(v.x), f2bf(v.y), f2bf(v.z), f2bf(v.w) };
            *(ushort4*)(a.hbf + i) = o4;
        }
        return;
    }
    b -= nbCast;
    if (b < 288) { trWT_body(a.W0, a.Wt0, 768, 384, b, t, tile); return; }
    b -= 288;
    if (b < 96)  { trWT_body(a.W2, a.Wt2, 256, 384, b, t, tile); return; }
    b -= 96;
    if (b < 96)  { trWT_body(a.W3, a.Wt3, 256, 384, b, t, tile); return; }
    b -= 96;
    if (b < 128)  { trLw_body(a.lw0, a.lwT0, 128, (long)b * 256 + t); return; }
    b -= 128;
    if (b < 384)  { trLw_body(a.lw1, a.lwT1, 384, (long)b * 256 + t); return; }
    b -= 384;
    if (b < 128)  { trLw_body(a.lw2, a.lwT2, 128, (long)b * 256 + t); return; }
    b -= 128;
    if (b < 128)  { trLw_body(a.lw3, a.lwT3, 128, (long)b * 256 + t); return; }
    b -= 128;
    if (b < 1728) {
        long idx = (long)b * 256 + t;
        int j = (int)(idx / 384), o = (int)(idx % 384);
        int h = j >> 10, rc = j & 1023;
        int r = rc >> 8, c = rc & 255;
        a.A2[idx] = f2bf(a.W1[((long)(r * 256 + c)) * 1152 + h * 384 + o] * (1.f / 3.f));
        return;
    }
    b -= 1728;
    if (b < nbAe) {
        int e = b * 256 + t;
        if (e >= E) return;
        float av[8];
#pragma unroll
        for (int d = 0; d < 8; ++d) av[d] = a.ea[(long)e * 8 + d];
#pragma unroll
        for (int l = 0; l < 4; ++l) {
#pragma unroll
            for (int h = 0; h < 3; ++h) {
                float s = 0.f;
#pragma unroll
                for (int d = 0; d < 8; ++d) s += av[d] * a.g[l * 24 + d * 3 + h];
                a.aeb[((size_t)l * E + e) * 3 + h] = s;
            }
        }
        return;
    }
    b -= nbAe;
    const int wid = t >> 6, lane = t & 63;
    if (b < 768) {
        int w = b * 4 + wid;
        int c = w / 24, j = w % 24;
        float s = 0.f;
        for (int o = lane; o < 256; o += 64) s += a.lw0[(long)c * 256 + o] * a.Wqk1[(long)o * 24 + j];
        s = wave_sum(s);
        if (lane == 0) a.lwT0[(256 + j) * 128 + c] = f2bf(s);
        return;
    }
    b -= 768;
    if (b < 768) {
        int w = b * 4 + wid;
        int c = w / 24, j = w % 24;
        float s = 0.f;
        for (int o = lane; o < 256; o += 64) s += a.lw2[(long)c * 256 + o] * a.Wqk3[(long)o * 24 + j];
        s = wave_sum(s);
        if (lane == 0) a.lwT2[(256 + j) * 128 + c] = f2bf(s);
        return;
    }
    b -= 768;
    if (b < 6) {
        int w = b * 4 + wid;
        if (w < 24) {
            float s = 0.f;
            for (int o = lane; o < 256; o += 64) s += a.lb0[o] * a.Wqk1[(long)o * 24 + w];
            s = wave_sum(s);
            if (lane == 0) a.qb1[w] = s;
        }
        return;
    }
    b -= 6;
    if (b < 6) {
        int w = b * 4 + wid;
        if (w < 24) {
            float s = 0.f;
            for (int o = lane; o < 256; o += 64) s += a.lb2[o] * a.Wqk3[(long)o * 24 + w];
            s = wave_sum(s);
            if (lane == 0) a.qb3[w] = s;
        }
        return;
    }
    b -= 6;
    if (b < 52) { a.lwT0[280 * 128 + b * 256 + t] = 0; return; }
    b -= 52;
    a.lwT2[280 * 128 + b * 256 + t] = 0;
}

// ---------------- qkn for layer 0 from xWb ----------------
__global__ __launch_bounds__(256)
void qkx_kernel(const ushort* __restrict__ xW, const float* __restrict__ q0,
                const float* __restrict__ k0, float* __restrict__ qkn, int N) {
    __shared__ float qv[6][384];
    const int t = threadIdx.x, wid = t >> 6, lane = t & 63;
    for (int i = t; i < 384; i += 256) {
        qv[0][i] = q0[i * 3 + 0]; qv[1][i] = q0[i * 3 + 1]; qv[2][i] = q0[i * 3 + 2];
        qv[3][i] = k0[i * 3 + 0]; qv[4][i] = k0[i * 3 + 1]; qv[5][i] = k0[i * 3 + 2];
    }
    __syncthreads();
    const int n = blockIdx.x * 4 + wid;
    if (n >= N) return;
    const ushort* row = xW + (long)n * 1536;
    float acc[24];
#pragma unroll
    for (int j = 0; j < 24; ++j) acc[j] = 0.f;
#pragma unroll
    for (int r = 0; r < 4; ++r) {
#pragma unroll
        for (int jj = 0; jj < 3; ++jj) {
            int o = jj * 128 + lane * 2;
            uint v = *(const uint*)(row + r * 384 + o);
            float x0 = bf2f((ushort)(v & 0xffffu));
            float x1 = bf2f((ushort)(v >> 16));
#pragma unroll
            for (int t6 = 0; t6 < 6; ++t6)
                acc[r * 6 + t6] += x0 * qv[t6][o] + x1 * qv[t6][o + 1];
        }
    }
#pragma unroll
    for (int j = 0; j < 24; ++j) {
        float v = wave_sum(acc[j]);
        if (lane == 0) qkn[(long)n * 24 + j] = v;
    }
}

// ---------------- bf16 MFMA GEMM (2-phase double-buffered) ----------------
template<int OUT_BF16, int DUAL, int PARTIAL, int QK>
__global__ __launch_bounds__(256, 5)
void gemm_bf16(const ushort* __restrict__ A, const ushort* __restrict__ Bt,
               void* __restrict__ Cp, ushort* __restrict__ C2,
               const float* __restrict__ bias,
               int M, int K, int ldc, int nbn, int nwg, int nbase, int Ks,
               float* __restrict__ qkn, const float* __restrict__ qb, int qkcol) {
    __shared__ ushort lA[2][128 * 32];
    __shared__ ushort lB[2][128 * 32];
    const int t = threadIdx.x;
    const int lane = t & 63;
    const int wid = t >> 6;

    int b = blockIdx.x;
    int q8 = nwg >> 3, r8 = nwg & 7;
    int xcd = b & 7, loc = b >> 3;
    int tt = (xcd < r8 ? xcd * (q8 + 1) : r8 * (q8 + 1) + (xcd - r8) * q8) + loc;
    const int slice = tt / nbase;
    const int tile = tt % nbase;
    const int kbase = slice * Ks;
    const int bm = (tile / nbn) * 128;
    const int bn = (tile % nbn) * 128;

    const int wr = (wid >> 1) * 64;
    const int wc = (wid & 1) * 64;

    f32x4 acc[4][4];
#pragma unroll
    for (int m = 0; m < 4; ++m)
#pragma unroll
        for (int nn = 0; nn < 4; ++nn) acc[m][nn] = (f32x4){0.f, 0.f, 0.f, 0.f};

    const int sr = t >> 2;
    const int sk = (((t & 3) ^ ((t >> 3) & 3)) * 8);
    long ar0 = bm + sr;      if (ar0 > M - 1) ar0 = M - 1;
    long ar1 = bm + sr + 64; if (ar1 > M - 1) ar1 = M - 1;
    const ushort* gA0 = A + ar0 * K + sk + kbase;
    const ushort* gA1 = A + ar1 * K + sk + kbase;
    const ushort* gB0 = Bt + (long)(bn + sr) * K + sk + kbase;
    const ushort* gB1 = Bt + (long)(bn + sr + 64) * K + sk + kbase;

    const int frow = lane & 15;
    const int pc8 = (((lane >> 4) ^ ((lane >> 1) & 3)) * 8);

    GLD_LDS(gA0, &lA[0][t * 8]);
    GLD_LDS(gA1, &lA[0][t * 8 + 64 * 32]);
    GLD_LDS(gB0, &lB[0][t * 8]);
    GLD_LDS(gB1, &lB[0][t * 8 + 64 * 32]);
    __syncthreads();

    int cur = 0;
    for (int k0 = 0; k0 < Ks; k0 += 32) {
        if (k0 + 32 < Ks) {
            int nb = cur ^ 1, kn = k0 + 32;
            GLD_LDS(gA0 + kn, &lA[nb][t * 8]);
            GLD_LDS(gA1 + kn, &lA[nb][t * 8 + 64 * 32]);
            GLD_LDS(gB0 + kn, &lB[nb][t * 8]);
            GLD_LDS(gB1 + kn, &lB[nb][t * 8 + 64 * 32]);
        }
        bf16x8 af[4], bff[4];
#pragma unroll
        for (int m = 0; m < 4; ++m)
            af[m] = *(const bf16x8*)&lA[cur][(wr + m * 16 + frow) * 32 + pc8];
#pragma unroll
        for (int nn = 0; nn < 4; ++nn)
            bff[nn] = *(const bf16x8*)&lB[cur][(wc + nn * 16 + frow) * 32 + pc8];
#pragma unroll
        for (int m = 0; m < 4; ++m)
#pragma unroll
            for (int nn = 0; nn < 4; ++nn)
                acc[m][nn] = __builtin_amdgcn_mfma_f32_16x16x32_bf16(af[m], bff[nn], acc[m][nn], 0, 0, 0);
        __syncthreads();
        cur ^= 1;
    }

    const int crow = (lane >> 4) * 4;
    const int ccol = lane & 15;
#pragma unroll
    for (int m = 0; m < 4; ++m) {
#pragma unroll
        for (int nn = 0; nn < 4; ++nn) {
            int col = bn + wc + nn * 16 + ccol;
#pragma unroll
            for (int r = 0; r < 4; ++r) {
                int row = bm + wr + m * 16 + crow + r;
                if (row < M) {
                    float v = acc[m][nn][r];
                    if (QK && col >= qkcol) {
                        int qc = col - qkcol;
                        if (qc < 24) qkn[(long)row * 24 + qc] = v + (qb ? qb[qc] : 0.f);
                    } else {
                        if (!PARTIAL && bias) v += bias[col];
                        if (PARTIAL) {
                            ((float*)Cp)[(size_t)slice * M * ldc + (long)row * ldc + col] = v;
                        } else {
                            if (OUT_BF16) ((ushort*)Cp)[(long)row * ldc + col] = f2bf(v);
                            else          ((float*)Cp)[(long)row * ldc + col] = v;
                            if (DUAL)     C2[(long)row * ldc + col] = f2bf(v);
                        }
                    }
                }
            }
        }
    }
}

// ---------------- split-K reduce + fused qk for layer 2 ----------------
__global__ __launch_bounds__(256)
void reduce3qk_kernel(const float* __restrict__ P, const float* __restrict__ bf2,
                      const float* __restrict__ Wqk2,
                      float* __restrict__ outf, ushort* __restrict__ outb,
                      float* __restrict__ qkn, int M) {
    const int wid = threadIdx.x >> 6, lane = threadIdx.x & 63;
    const int n = blockIdx.x * 4 + wid;
    if (n >= M) return;
    long off = (long)n * 256 + lane * 4;
    const long stride = (long)M * 256;
    float4 a = *(const float4*)(P + off);
    float4 b = *(const float4*)(P + stride + off);
    float4 c = *(const float4*)(P + 2 * stride + off);
    float4 bs = *(const float4*)(bf2 + lane * 4);
    float rr[4] = { a.x + b.x + c.x + bs.x, a.y + b.y + c.y + bs.y,
                    a.z + b.z + c.z + bs.z, a.w + b.w + c.w + bs.w };
    float4 r4 = { rr[0], rr[1], rr[2], rr[3] };
    *(float4*)(outf + off) = r4;
    ushort4 o4 = { f2bf(rr[0]), f2bf(rr[1]), f2bf(rr[2]), f2bf(rr[3]) };
    *(ushort4*)(outb + off) = o4;
    float acc[24];
#pragma unroll
    for (int j = 0; j < 24; ++j) acc[j] = 0.f;
#pragma unroll
    for (int i = 0; i < 4; ++i) {
        const float* wr = Wqk2 + (long)(lane * 4 + i) * 24;
        float hv = rr[i];
#pragma unroll
        for (int j = 0; j < 24; ++j) acc[j] += hv * wr[j];
    }
#pragma unroll
    for (int j = 0; j < 24; ++j) {
        float v = wave_sum(acc[j]);
        if (lane == 0) qkn[(long)n * 24 + j] = v;
    }
}

// ================= attention (wave-per-node, 4-slot pipelined gather) =================
__global__ __launch_bounds__(256)
void attn_kernel(const float* __restrict__ qkn, const ushort* __restrict__ xW,
                 const float* __restrict__ ae, const int* __restrict__ offs,
                 const int* __restrict__ csr, const int* __restrict__ srcv,
                 const int* __restrict__ etv, const float* __restrict__ bias,
                 ushort* __restrict__ out, int N, int ldx) {
    __shared__ float4 pk_sh[4][64];
    __shared__ float red[4][384];
    const int wid = threadIdx.x >> 6, lane = threadIdx.x & 63;
    const int n = blockIdx.x * 4 + wid;
    if (n >= N) return;
    const int e0 = offs[n];
    const int deg = offs[n + 1] - e0;
    const float* qd = qkn + (long)n * 24;

    float m0 = -1e30f, m1 = -1e30f, m2 = -1e30f;
    for (int base = 0; base < deg; base += 64) {
        int idx = base + lane;
        if (idx < deg) {
            int eid = csr[e0 + idx];
            int s_ = srcv[eid], t_ = etv[eid];
            const float* qs = qkn + (long)s_ * 24 + t_ * 6;
            const float* a3 = ae + (long)eid * 3;
            float v0 = qd[t_ * 6 + 0] + qs[3] + a3[0];
            float v1 = qd[t_ * 6 + 1] + qs[4] + a3[1];
            float v2 = qd[t_ * 6 + 2] + qs[5] + a3[2];
            v0 = v0 > 0.f ? v0 : 0.2f * v0;
            v1 = v1 > 0.f ? v1 : 0.2f * v1;
            v2 = v2 > 0.f ? v2 : 0.2f * v2;
            m0 = fmaxf(m0, v0); m1 = fmaxf(m1, v1); m2 = fmaxf(m2, v2);
        }
    }
    m0 = wave_max(m0); m1 = wave_max(m1); m2 = wave_max(m2);

    float acc[6] = {0.f, 0.f, 0.f, 0.f, 0.f, 0.f};
    float ps0 = 0.f, ps1 = 0.f, ps2 = 0.f;

    for (int base = 0; base < deg; base += 64) {
        int cnt2 = deg - base; if (cnt2 > 64) cnt2 = 64;
        if (lane < cnt2) {
            int eid = csr[e0 + base + lane];
            int s_ = srcv[eid], t_ = etv[eid];
            const float* qs = qkn + (long)s_ * 24 + t_ * 6;
            const float* a3 = ae + (long)eid * 3;
            float v0 = qd[t_ * 6 + 0] + qs[3] + a3[0];
            float v1 = qd[t_ * 6 + 1] + qs[4] + a3[1];
            float v2 = qd[t_ * 6 + 2] + qs[5] + a3[2];
            v0 = v0 > 0.f ? v0 : 0.2f * v0;
            v1 = v1 > 0.f ? v1 : 0.2f * v1;
            v2 = v2 > 0.f ? v2 : 0.2f * v2;
            float p0 = __expf(v0 - m0), p1 = __expf(v1 - m1), p2 = __expf(v2 - m2);
            pk_sh[wid][lane] = make_float4(p0, p1, p2, __int_as_float((s_ << 2) | t_));
            ps0 += p0; ps1 += p1; ps2 += p2;
        }
        wave_sync();
        float4 pk0 = {0,0,0,0}, pk1 = {0,0,0,0}, pk2 = {0,0,0,0}, pk3 = {0,0,0,0};
        uint a0 = 0, b0 = 0, c0 = 0, a1 = 0, b1 = 0, c1 = 0;
        uint a2 = 0, b2 = 0, c2 = 0, a3 = 0, b3 = 0, c3 = 0;
#define LDE(S, J) { pk##S = pk_sh[wid][J]; int pk_ = __float_as_int(pk##S.w); \
    const uint* xr = (const uint*)(xW + (long)(pk_ >> 2) * ldx + (pk_ & 3) * 384); \
    a##S = xr[lane]; b##S = xr[lane + 64]; c##S = xr[lane + 128]; }
#define ACCE(S) { \
    acc[0] += pk##S.x * bf2f((ushort)(a##S & 0xffffu)); \
    acc[1] += pk##S.x * bf2f((ushort)(a##S >> 16)); \
    acc[2] += pk##S.y * bf2f((ushort)(b##S & 0xffffu)); \
    acc[3] += pk##S.y * bf2f((ushort)(b##S >> 16)); \
    acc[4] += pk##S.z * bf2f((ushort)(c##S & 0xffffu)); \
    acc[5] += pk##S.z * bf2f((ushort)(c##S >> 16)); }
        if (0 < cnt2) LDE(0, 0);
        if (1 < cnt2) LDE(1, 1);
        if (2 < cnt2) LDE(2, 2);
        if (3 < cnt2) LDE(3, 3);
        for (int j = 0; j < cnt2; j += 4) {
            { ACCE(0); if (j + 4 < cnt2) LDE(0, j + 4); }
            if (j + 1 < cnt2) { ACCE(1); if (j + 5 < cnt2) LDE(1, j + 5); }
            if (j + 2 < cnt2) { ACCE(2); if (j + 6 < cnt2) LDE(2, j + 6); }
            if (j + 3 < cnt2) { ACCE(3); if (j + 7 < cnt2) LDE(3, j + 7); }
        }
#undef LDE
#undef ACCE
        wave_sync();
    }
    ps0 = wave_sum(ps0); ps1 = wave_sum(ps1); ps2 = wave_sum(ps2);
    float i0 = 1.f / fmaxf(ps0, 1e-16f);
    float i1 = 1.f / fmaxf(ps1, 1e-16f);
    float i2 = 1.f / fmaxf(ps2, 1e-16f);
    red[wid][2 * lane]           = acc[0] * i0;
    red[wid][2 * lane + 1]       = acc[1] * i0;
    red[wid][128 + 2 * lane]     = acc[2] * i1;
    red[wid][128 + 2 * lane + 1] = acc[3] * i1;
    red[wid][256 + 2 * lane]     = acc[4] * i2;
    red[wid][256 + 2 * lane + 1] = acc[5] * i2;
    wave_sync();
    for (int o = lane; o < 128; o += 64) {
        float v = (red[wid][o] + red[wid][128 + o] + red[wid][256 + o]) * (1.f / 3.f) + bias[o];
        out[(long)n * 128 + o] = f2bf(v);
    }
}

// layer 2: Z-accumulation (wave-per-node, 4-slot pipelined gather)
__global__ __launch_bounds__(256)
void attn2_kernel(const float* __restrict__ qkn, const ushort* __restrict__ hbf,
                  const float* __restrict__ ae, const int* __restrict__ offs,
                  const int* __restrict__ csr, const int* __restrict__ srcv,
                  const int* __restrict__ etv, ushort* __restrict__ Z, int N) {
    __shared__ float4 pk_sh[4][64];
    const int wid = threadIdx.x >> 6, lane = threadIdx.x & 63;
    const int n = blockIdx.x * 4 + wid;
    if (n >= N) return;
    const int e0 = offs[n];
    const int deg = offs[n + 1] - e0;
    const float* qd = qkn + (long)n * 24;

    float m0 = -1e30f, m1 = -1e30f, m2 = -1e30f;
    for (int base = 0; base < deg; base += 64) {
        int idx = base + lane;
        if (idx < deg) {
            int eid = csr[e0 + idx];
            int s_ = srcv[eid], t_ = etv[eid];
            const float* qs = qkn + (long)s_ * 24 + t_ * 6;
            const float* a3 = ae + (long)eid * 3;
            float v0 = qd[t_ * 6 + 0] + qs[3] + a3[0];
            float v1 = qd[t_ * 6 + 1] + qs[4] + a3[1];
            float v2 = qd[t_ * 6 + 2] + qs[5] + a3[2];
            v0 = v0 > 0.f ? v0 : 0.2f * v0;
            v1 = v1 > 0.f ? v1 : 0.2f * v1;
            v2 = v2 > 0.f ? v2 : 0.2f * v2;
            m0 = fmaxf(m0, v0); m1 = fmaxf(m1, v1); m2 = fmaxf(m2, v2);
        }
    }
    m0 = wave_max(m0); m1 = wave_max(m1); m2 = wave_max(m2);

    float acc[48];
#pragma unroll
    for (int i = 0; i < 48; ++i) acc[i] = 0.f;
    float ps0 = 0.f, ps1 = 0.f, ps2 = 0.f;

    for (int base = 0; base < deg; base += 64) {
        int cnt2 = deg - base; if (cnt2 > 64) cnt2 = 64;
        if (lane < cnt2) {
            int eid = csr[e0 + base + lane];
            int s_ = srcv[eid], t_ = etv[eid];
            const float* qs = qkn + (long)s_ * 24 + t_ * 6;
            const float* a3 = ae + (long)eid * 3;
            float v0 = qd[t_ * 6 + 0] + qs[3] + a3[0];
            float v1 = qd[t_ * 6 + 1] + qs[4] + a3[1];
            float v2 = qd[t_ * 6 + 2] + qs[5] + a3[2];
            v0 = v0 > 0.f ? v0 : 0.2f * v0;
            v1 = v1 > 0.f ? v1 : 0.2f * v1;
            v2 = v2 > 0.f ? v2 : 0.2f * v2;
            float p0 = __expf(v0 - m0), p1 = __expf(v1 - m1), p2 = __expf(v2 - m2);
            pk_sh[wid][lane] = make_float4(p0, p1, p2, __int_as_float((s_ << 2) | t_));
            ps0 += p0; ps1 += p1; ps2 += p2;
        }
        wave_sync();
        float4 pk0 = {0,0,0,0}, pk1 = {0,0,0,0}, pk2 = {0,0,0,0}, pk3 = {0,0,0,0};
        uint2 v0_ = {0,0}, v1_ = {0,0}, v2_ = {0,0}, v3_ = {0,0};
#define LDE2(S, J) { pk##S = pk_sh[wid][J]; \
    v##S##_ = *(const uint2*)(hbf + ((long)(__float_as_int(pk##S.w) >> 2)) * 256 + lane * 4); }
#define UPDR(R) { \
    acc[(R)*4+0] += px * x0; acc[(R)*4+1] += px * x1; acc[(R)*4+2] += px * x2; acc[(R)*4+3] += px * x3; \
    acc[16+(R)*4+0] += py * x0; acc[16+(R)*4+1] += py * x1; acc[16+(R)*4+2] += py * x2; acc[16+(R)*4+3] += py * x3; \
    acc[32+(R)*4+0] += pz * x0; acc[32+(R)*4+1] += pz * x1; acc[32+(R)*4+2] += pz * x2; acc[32+(R)*4+3] += pz * x3; }
#define ACC2(S) { int r_ = __float_as_int(pk##S.w) & 3; \
    float x0 = bf2f((ushort)(v##S##_.x & 0xffffu)), x1 = bf2f((ushort)(v##S##_.x >> 16)); \
    float x2 = bf2f((ushort)(v##S##_.y & 0xffffu)), x3 = bf2f((ushort)(v##S##_.y >> 16)); \
    float px = pk##S.x, py = pk##S.y, pz = pk##S.z; \
    if (r_ == 0) UPDR(0) else if (r_ == 1) UPDR(1) else if (r_ == 2) UPDR(2) else UPDR(3) }
        if (0 < cnt2) LDE2(0, 0);
        if (1 < cnt2) LDE2(1, 1);
        if (2 < cnt2) LDE2(2, 2);
        if (3 < cnt2) LDE2(3, 3);
        for (int j = 0; j < cnt2; j += 4) {
            { ACC2(0); if (j + 4 < cnt2) LDE2(0, j + 4); }
            if (j + 1 < cnt2) { ACC2(1); if (j + 5 < cnt2) LDE2(1, j + 5); }
            if (j + 2 < cnt2) { ACC2(2); if (j + 6 < cnt2) LDE2(2, j + 6); }
            if (j + 3 < cnt2) { ACC2(3); if (j + 7 < cnt2) LDE2(3, j + 7); }
        }
#undef LDE2
#undef UPDR
#undef ACC2
        wave_sync();
    }
    ps0 = wave_sum(ps0); ps1 = wave_sum(ps1); ps2 = wave_sum(ps2);
    float inv0 = 1.f / fmaxf(ps0, 1e-16f);
    float inv1 = 1.f / fmaxf(ps1, 1e-16f);
    float inv2 = 1.f / fmaxf(ps2, 1e-16f);
    ushort* zr = Z + (long)n * 3072 + lane * 4;
#pragma unroll
    for (int h = 0; h < 3; ++h) {
        float iv = (h == 0) ? inv0 : (h == 1 ? inv1 : inv2);
#pragma unroll
        for (int r = 0; r < 4; ++r) {
            const float* a4 = acc + h * 16 + r * 4;
            ushort4 o4 = { f2bf(a4[0] * iv), f2bf(a4[1] * iv),
                           f2bf(a4[2] * iv), f2bf(a4[3] * iv) };
            *(ushort4*)(zr + h * 1024 + r * 256) = o4;
        }
    }
}

// ---------------- final: hole-node softmax ----------------
__global__ void softmax_kernel(const float* __restrict__ h, const int* __restrict__ hole,
                               float* __restrict__ out, int B) {
    int b = blockIdx.x;
    int t = threadIdx.x;
    int lane = t & 63, wid = t >> 6;
    __shared__ float sm[4];
    __shared__ float ss[4];
    int row = hole[b];
    float v = h[(long)row * 256 + t];
    float m = v;
#pragma unroll
    for (int d = 32; d >= 1; d >>= 1) m = fmaxf(m, __shfl_xor(m, d));
    if (lane == 0) sm[wid] = m;
    __syncthreads();
    m = fmaxf(fmaxf(sm[0], sm[1]), fmaxf(sm[2], sm[3]));
    float ex = __expf(v - m);
    float s = ex;
#pragma unroll
    for (int d = 32; d >= 1; d >>= 1) s += __shfl_xor(s, d);
    if (lane == 0) ss[wid] = s;
    __syncthreads();
    s = ss[0] + ss[1] + ss[2] + ss[3];
    out[(long)b * 256 + t] = ex / s;
}

// ---------------- host ----------------
extern "C" void kernel_launch(void* const* d_in, const int* in_sizes, int n_in,
                              void* d_out, int out_size, void* d_ws, size_t ws_size,
                              hipStream_t stream) {
    const float* x   = (const float*)d_in[0];
    const int*   ei  = (const int*)d_in[1];
    const int*   ety = (const int*)d_in[2];
    const float* ea  = (const float*)d_in[3];
    const int*   bat = (const int*)d_in[4];

    const int N = in_sizes[0] / 768;
    const int E = in_sizes[2];
    const int B = out_size / 256;

    static const int CIN[4]  = {768, 256, 256, 256};
    static const int COUT[4] = {128, 384, 128, 128};
    static const int NCC[4]  = {1536, 4608, 1536, 1536};

    const float *Wp[4], *qp[4], *kp[4], *lep[4], *ep[4], *bp[4], *lwp[4], *lbp[4];
    for (int l = 0; l < 4; ++l) {
        Wp[l]  = (const float*)d_in[5 + 6 * l];
        qp[l]  = (const float*)d_in[6 + 6 * l];
        kp[l]  = (const float*)d_in[7 + 6 * l];
        lep[l] = (const float*)d_in[8 + 6 * l];
        ep[l]  = (const float*)d_in[9 + 6 * l];
        bp[l]  = (const float*)d_in[10 + 6 * l];
        lwp[l] = (const float*)d_in[29 + 2 * l];
        lbp[l] = (const float*)d_in[30 + 2 * l];
    }

    char* ws = (char*)d_ws;
    size_t pos = 0;
    auto carve = [&](size_t bytes) -> char* {
        char* r = ws + pos;
        pos += (bytes + 255) & ~(size_t)255;
        return r;
    };
    ushort *Wt[4], *lwT[4];
    float* Wqk[4];
    for (int l = 0; l < 4; ++l) Wt[l]  = (ushort*)carve(l == 1 ? 0 : (size_t)2 * NCC[l] * CIN[l]);
    for (int l = 0; l < 4; ++l) lwT[l] = (ushort*)carve((size_t)2 * 384 * COUT[l]);
    for (int l = 0; l < 4; ++l) Wqk[l] = (float*)carve((size_t)4 * 24 * CIN[l]);
    float*  gbuf  = (float*)carve(4 * 24 * 4);
    float*  aeb   = (float*)carve((size_t)4 * E * 3 * 4);
    float*  qkn   = (float*)carve((size_t)N * 24 * 4);
    float*  qb1   = (float*)carve(24 * 4);
    float*  qb3   = (float*)carve(24 * 4);
    ushort* hbf   = (ushort*)carve((size_t)N * 768 * 2);
    ushort* xWb   = (ushort*)carve((size_t)N * 1536 * 2);   // also split-K fp32 partials
    ushort* Zb    = (ushort*)carve((size_t)N * 3072 * 2);
    ushort* A2    = (ushort*)carve((size_t)3072 * 384 * 2);
    ushort* W2T   = (ushort*)carve((size_t)256 * 3072 * 2);
    float*  bf2   = (float*)carve(256 * 4);
    ushort* convbf= (ushort*)carve((size_t)N * 384 * 2);
    float*  hbuf  = (float*)carve((size_t)N * 256 * 4);
    int* cnt  = (int*)carve((size_t)N * 4);
    int* cur  = (int*)carve((size_t)N * 4);
    int* offs = (int*)carve((size_t)(N + 1) * 4);
    int* csr  = (int*)carve((size_t)E * 4);
    int* hole = (int*)carve((size_t)B * 4);

    hipMemsetAsync(cnt, 0, (size_t)((char*)cur - (char*)cnt) + (size_t)N * 4, stream);
    hipMemsetAsync(hole, 0x7f, (size_t)B * 4, stream);

    const int* dst = ei + E;
    int nbEH = ((E > N ? E : N) + 255) / 256;
    deg_hole_kernel<<<nbEH, 256, 0, stream>>>(dst, cnt, bat, hole, E, N);
    scan_kernel<<<1, 1024, 0, stream>>>(cnt, offs, N);
    fill_kernel<<<(E + 255) / 256, 256, 0, stream>>>(dst, offs, cur, csr, E);

    PrepSArgs psa = { Wp[1], Wp[2], Wp[3], qp[1], qp[2], qp[3],
                      kp[1], kp[2], kp[3], Wqk[1], Wqk[2], Wqk[3],
                      lep[0], lep[1], lep[2], lep[3], ep[0], ep[1], ep[2], ep[3],
                      gbuf, bp[1], lwp[1], lbp[1], bf2 };
    preps_kernel<<<(3424 + 3) / 4, 256, 0, stream>>>(psa);

    long nCast = (long)N * 768;
    int nbCast = (int)((nCast / 4 + 255) / 256);
    int nbAe = (E + 255) / 256;
    PrepWArgs pw = { x, Wp[0], Wp[2], Wp[3], lwp[0], lwp[1], lwp[2], lwp[3], Wp[1],
                     hbf, Wt[0], Wt[2], Wt[3], lwT[0], lwT[1], lwT[2], lwT[3], A2,
                     ea, gbuf, aeb, Wqk[1], Wqk[3], lbp[0], lbp[2], qb1, qb3 };
    prepw_kernel<<<nbCast + nbAe + 4628, 256, 0, stream>>>(pw, nbCast, nCast, E, nbAe);

    gemm_bf16<1, 0, 0, 0><<<48, 256, 0, stream>>>(lwT[1], A2, (void*)W2T, nullptr, nullptr,
                                                  256, 384, 3072, 24, 48, 48, 384,
                                                  nullptr, nullptr, 0);

    const int nbm = (N + 127) / 128;
    for (int l = 0; l < 4; ++l) {
        if (l == 1) {
            attn2_kernel<<<(N + 3) / 4, 256, 0, stream>>>(qkn, hbf, aeb + (size_t)l * E * 3,
                                                          offs, csr, ei, ety, Zb, N);
            int nbase = nbm * 2, nwgS = nbase * 3;
            gemm_bf16<0, 0, 1, 0><<<nwgS, 256, 0, stream>>>(Zb, W2T, (void*)xWb, nullptr, nullptr,
                                                            N, 3072, 256, 2, nwgS, nbase, 1024,
                                                            nullptr, nullptr, 0);
            reduce3qk_kernel<<<(N + 3) / 4, 256, 0, stream>>>((const float*)xWb, bf2, Wqk[2],
                                                              hbuf, hbf, qkn, N);
        } else {
            int nbn1 = NCC[l] / 128, nwg1 = nbm * nbn1;
            gemm_bf16<1, 0, 0, 0><<<nwg1, 256, 0, stream>>>(hbf, Wt[l], (void*)xWb, nullptr,
                                                            nullptr, N, CIN[l], NCC[l], nbn1,
                                                            nwg1, nwg1, CIN[l],
                                                            nullptr, nullptr, 0);
            if (l == 0)
                qkx_kernel<<<(N + 3) / 4, 256, 0, stream>>>(xWb, qp[0], kp[0], qkn, N);
            attn_kernel<<<(N + 3) / 4, 256, 0, stream>>>(qkn, xWb, aeb + (size_t)l * E * 3,
                                                         offs, csr, ei, ety, bp[l], convbf, N, 1536);
            if (l == 3) {
                int nwg2 = nbm * 2;
                gemm_bf16<0, 0, 0, 0><<<nwg2, 256, 0, stream>>>(convbf, lwT[3], (void*)hbuf, nullptr,
                                                                lbp[3], N, 128, 256, 2, nwg2, nwg2, 128,
                                                                nullptr, nullptr, 0);
            } else {
                float* qbp = (l == 0) ? qb1 : qb3;
                int nwg2 = nbm * 3;
                gemm_bf16<0, 1, 0, 1><<<nwg2, 256, 0, stream>>>(convbf, lwT[l], (void*)hbuf, hbf,
                                                                lbp[l], N, 128, 256, 3, nwg2, nwg2, 128,
                                                                qkn, qbp, 256);
            }
        }
    }
    softmax_kernel<<<B, 256, 0, stream>>>(hbuf, hole, (float*)d_out, B);
}

// Round 19
// 450.180 us; speedup vs baseline: 1.9528x; 1.0310x over previous
//
#include <hip/hip_runtime.h>

typedef unsigned int uint;
typedef unsigned short ushort;
typedef __attribute__((ext_vector_type(8))) short bf16x8;
typedef __attribute__((ext_vector_type(4))) float f32x4;

#define GLD_LDS(g, l) __builtin_amdgcn_global_load_lds( \
    (const __attribute__((address_space(1))) void*)(g), \
    (__attribute__((address_space(3))) void*)(l), 16, 0, 0)

__device__ __forceinline__ ushort f2bf(float f) {
    uint u = __builtin_bit_cast(uint, f);
    u += 0x7fffu + ((u >> 16) & 1u);
    return (ushort)(u >> 16);
}
__device__ __forceinline__ float bf2f(ushort s) {
    uint u = ((uint)s) << 16;
    return __builtin_bit_cast(float, u);
}
__device__ __forceinline__ void wave_sync() {
    asm volatile("s_waitcnt lgkmcnt(0)" ::: "memory");
}
__device__ __forceinline__ float wave_sum(float v) {
#pragma unroll
    for (int d = 32; d >= 1; d >>= 1) v += __shfl_xor(v, d);
    return v;
}

// ---------------- CSR build ----------------
__global__ void deg_hole_kernel(const int* __restrict__ dst, int* __restrict__ cnt,
                                const int* __restrict__ bat, int* __restrict__ hole,
                                int E, int N) {
    int e = blockIdx.x * 256 + threadIdx.x;
    if (e < E) atomicAdd(&cnt[dst[e]], 1);
    if (e < N) atomicMin(&hole[bat[e]], e);
}

__global__ void scan_kernel(const int* __restrict__ cnt, int* __restrict__ offs, int n) {
    __shared__ int part[1024];
    const int t = threadIdx.x;
    const int strip = (n + 1023) / 1024;
    int s = 0;
    for (int i = 0; i < strip; ++i) {
        int idx = t * strip + i;
        if (idx < n) s += cnt[idx];
    }
    part[t] = s;
    __syncthreads();
    for (int d = 1; d < 1024; d <<= 1) {
        int v = (t >= d) ? part[t - d] : 0;
        __syncthreads();
        part[t] += v;
        __syncthreads();
    }
    int run = (t == 0) ? 0 : part[t - 1];
    for (int i = 0; i < strip; ++i) {
        int idx = t * strip + i;
        if (idx < n) { offs[idx] = run; run += cnt[idx]; }
    }
    if (t == 1023) offs[n] = part[1023];
}

__global__ void fill_kernel(const int* __restrict__ dst, const int* __restrict__ offs,
                            int* __restrict__ cur, int* __restrict__ csr, int E) {
    int e = blockIdx.x * 256 + threadIdx.x;
    if (e < E) {
        int d = dst[e];
        int p = offs[d] + atomicAdd(&cur[d], 1);
        csr[p] = e;
    }
}

// ---------------- fused small reductions (wave-granular regions) ----------------
struct PrepSArgs {
    const float *W1, *W2, *W3, *q1, *q2, *q3, *k1, *k2, *k3;
    float *Wqk1, *Wqk2, *Wqk3;
    const float *le0, *le1, *le2, *le3, *e0, *e1, *e2, *e3;
    float* g;
    const float *b2, *lw2l, *lb2;
    float* bf2;
};

__device__ __forceinline__ void wqk_body(const float* W, const float* q, const float* k,
                                         float* Wqk, int cin, int ho, int i, int lane) {
    int c = i >> 2, r = i & 3;
    const float* wrow = W + ((long)r * cin + c) * ho;
    float sq0 = 0.f, sq1 = 0.f, sq2 = 0.f, sk0 = 0.f, sk1 = 0.f, sk2 = 0.f;
    for (int o = lane; o < ho; o += 64) {
        float w = wrow[o];
        sq0 += w * q[(long)o * 3 + 0];
        sq1 += w * q[(long)o * 3 + 1];
        sq2 += w * q[(long)o * 3 + 2];
        sk0 += w * k[(long)o * 3 + 0];
        sk1 += w * k[(long)o * 3 + 1];
        sk2 += w * k[(long)o * 3 + 2];
    }
    sq0 = wave_sum(sq0); sq1 = wave_sum(sq1); sq2 = wave_sum(sq2);
    sk0 = wave_sum(sk0); sk1 = wave_sum(sk1); sk2 = wave_sum(sk2);
    if (lane == 0) {
        float* w6 = Wqk + (long)c * 24 + r * 6;
        w6[0] = sq0; w6[1] = sq1; w6[2] = sq2;
        w6[3] = sk0; w6[4] = sk1; w6[5] = sk2;
    }
}

__global__ __launch_bounds__(256)
void preps_kernel(PrepSArgs a) {
    const int wid = threadIdx.x >> 6, lane = threadIdx.x & 63;
    int w = blockIdx.x * 4 + wid;
    if (w < 96) {
        int l = w / 24, j = w % 24;
        int d = j / 3, h = j % 3;
        const float* le = (l == 0) ? a.le0 : (l == 1 ? a.le1 : (l == 2 ? a.le2 : a.le3));
        const float* e  = (l == 0) ? a.e0  : (l == 1 ? a.e1  : (l == 2 ? a.e2  : a.e3));
        int ho = (l == 1) ? 1152 : 384;
        float s = 0.f;
        for (int o = lane; o < ho; o += 64) s += le[(long)d * ho + o] * e[(long)o * 3 + h];
        s = wave_sum(s);
        if (lane == 0) a.g[l * 24 + j] = s;
        return;
    }
    w -= 96;
    if (w < 1024) { wqk_body(a.W1, a.q1, a.k1, a.Wqk1, 256, 1152, w, lane); return; }
    w -= 1024;
    if (w < 1024) { wqk_body(a.W2, a.q2, a.k2, a.Wqk2, 256, 384, w, lane); return; }
    w -= 1024;
    if (w < 1024) { wqk_body(a.W3, a.q3, a.k3, a.Wqk3, 256, 384, w, lane); return; }
    w -= 1024;
    if (w < 256) {
        float s = 0.f;
        for (int o = lane; o < 384; o += 64) s += a.b2[o] * a.lw2l[(long)o * 256 + w];
        s = wave_sum(s);
        if (lane == 0) a.bf2[w] = s + a.lb2[w];
    }
}

// ---------------- fused weight prep + ae + qk-fold weights (regions) ----------------
struct PrepWArgs {
    const float *x, *W0, *W2, *W3, *lw0, *lw1, *lw2, *lw3, *W1;
    ushort *hbf, *Wt0, *Wt2, *Wt3, *lwT0, *lwT1, *lwT2, *lwT3, *A2;
    const float *ea, *g;
    float* aeb;
    const float *Wqk1, *Wqk3, *lb0, *lb2;
    float *qb1, *qb3;
};

__device__ __forceinline__ void trLw_body(const float* lw, ushort* lwT, int cout_in, long idx) {
    int o = (int)(idx / cout_in);
    int c = (int)(idx % cout_in);
    lwT[idx] = f2bf(lw[(long)c * 256 + o]);
}

__device__ __forceinline__ void trWT_body(const float* W, ushort* Wt, int cin, int ho,
                                          int bt, int t, float (*tile)[65]) {
    const int tpo = ho / 64;
    const int tpc = cin / 64;
    const int per_r = tpc * tpo;
    int r = bt / per_r, rem = bt % per_r;
    int c0 = (rem / tpo) * 64, o0 = (rem % tpo) * 64;
    const int ti = t >> 6, tj = t & 63;
#pragma unroll
    for (int p = 0; p < 16; ++p) {
        int c = c0 + ti + 4 * p;
        tile[ti + 4 * p][tj] = W[((long)r * cin + c) * ho + o0 + tj];
    }
    __syncthreads();
#pragma unroll
    for (int p = 0; p < 16; ++p) {
        int o = o0 + ti + 4 * p;
        Wt[((long)(r * ho + o)) * cin + c0 + tj] = f2bf(tile[tj][ti + 4 * p]);
    }
}

__global__ __launch_bounds__(256)
void prepw_kernel(PrepWArgs a, int nbCast, long nCast, int E, int nbAe) {
    __shared__ float tile[64][65];
    int b = blockIdx.x;
    const int t = threadIdx.x;
    if (b < nbCast) {
        long i = ((long)b * 256 + t) * 4;
        if (i + 4 <= nCast) {
            float4 v = *(const float4*)(a.x + i);
            ushort4 o4 = { f2bf(v.x), f2bf(v.y), f2bf(v.z), f2bf(v.w) };
            *(ushort4*)(a.hbf + i) = o4;
        }
        return;
    }
    b -= nbCast;
    if (b < 288) { trWT_body(a.W0, a.Wt0, 768, 384, b, t, tile); return; }
    b -= 288;
    if (b < 96)  { trWT_body(a.W2, a.Wt2, 256, 384, b, t, tile); return; }
    b -= 96;
    if (b < 96)  { trWT_body(a.W3, a.Wt3, 256, 384, b, t, tile); return; }
    b -= 96;
    if (b < 128)  { trLw_body(a.lw0, a.lwT0, 128, (long)b * 256 + t); return; }
    b -= 128;
    if (b < 384)  { trLw_body(a.lw1, a.lwT1, 384, (long)b * 256 + t); return; }
    b -= 384;
    if (b < 128)  { trLw_body(a.lw2, a.lwT2, 128, (long)b * 256 + t); return; }
    b -= 128;
    if (b < 128)  { trLw_body(a.lw3, a.lwT3, 128, (long)b * 256 + t); return; }
    b -= 128;
    if (b < 1728) {
        long idx = (long)b * 256 + t;
        int j = (int)(idx / 384), o = (int)(idx % 384);
        int h = j >> 10, rc = j & 1023;
        int r = rc >> 8, c = rc & 255;
        a.A2[idx] = f2bf(a.W1[((long)(r * 256 + c)) * 1152 + h * 384 + o] * (1.f / 3.f));
        return;
    }
    b -= 1728;
    if (b < nbAe) {
        int e = b * 256 + t;
        if (e >= E) return;
        float av[8];
#pragma unroll
        for (int d = 0; d < 8; ++d) av[d] = a.ea[(long)e * 8 + d];
#pragma unroll
        for (int l = 0; l < 4; ++l) {
#pragma unroll
            for (int h = 0; h < 3; ++h) {
                float s = 0.f;
#pragma unroll
                for (int d = 0; d < 8; ++d) s += av[d] * a.g[l * 24 + d * 3 + h];
                a.aeb[((size_t)l * E + e) * 3 + h] = s;
            }
        }
        return;
    }
    b -= nbAe;
    const int wid = t >> 6, lane = t & 63;
    if (b < 768) {
        int w = b * 4 + wid;
        int c = w / 24, j = w % 24;
        float s = 0.f;
        for (int o = lane; o < 256; o += 64) s += a.lw0[(long)c * 256 + o] * a.Wqk1[(long)o * 24 + j];
        s = wave_sum(s);
        if (lane == 0) a.lwT0[(256 + j) * 128 + c] = f2bf(s);
        return;
    }
    b -= 768;
    if (b < 768) {
        int w = b * 4 + wid;
        int c = w / 24, j = w % 24;
        float s = 0.f;
        for (int o = lane; o < 256; o += 64) s += a.lw2[(long)c * 256 + o] * a.Wqk3[(long)o * 24 + j];
        s = wave_sum(s);
        if (lane == 0) a.lwT2[(256 + j) * 128 + c] = f2bf(s);
        return;
    }
    b -= 768;
    if (b < 6) {
        int w = b * 4 + wid;
        if (w < 24) {
            float s = 0.f;
            for (int o = lane; o < 256; o += 64) s += a.lb0[o] * a.Wqk1[(long)o * 24 + w];
            s = wave_sum(s);
            if (lane == 0) a.qb1[w] = s;
        }
        return;
    }
    b -= 6;
    if (b < 6) {
        int w = b * 4 + wid;
        if (w < 24) {
            float s = 0.f;
            for (int o = lane; o < 256; o += 64) s += a.lb2[o] * a.Wqk3[(long)o * 24 + w];
            s = wave_sum(s);
            if (lane == 0) a.qb3[w] = s;
        }
        return;
    }
    b -= 6;
    if (b < 52) { a.lwT0[280 * 128 + b * 256 + t] = 0; return; }
    b -= 52;
    a.lwT2[280 * 128 + b * 256 + t] = 0;
}

// ---------------- qkn for layer 0 from xWb ----------------
__global__ __launch_bounds__(256)
void qkx_kernel(const ushort* __restrict__ xW, const float* __restrict__ q0,
                const float* __restrict__ k0, float* __restrict__ qkn, int N) {
    __shared__ float qv[6][384];
    const int t = threadIdx.x, wid = t >> 6, lane = t & 63;
    for (int i = t; i < 384; i += 256) {
        qv[0][i] = q0[i * 3 + 0]; qv[1][i] = q0[i * 3 + 1]; qv[2][i] = q0[i * 3 + 2];
        qv[3][i] = k0[i * 3 + 0]; qv[4][i] = k0[i * 3 + 1]; qv[5][i] = k0[i * 3 + 2];
    }
    __syncthreads();
    const int n = blockIdx.x * 4 + wid;
    if (n >= N) return;
    const ushort* row = xW + (long)n * 1536;
    float acc[24];
#pragma unroll
    for (int j = 0; j < 24; ++j) acc[j] = 0.f;
#pragma unroll
    for (int r = 0; r < 4; ++r) {
#pragma unroll
        for (int jj = 0; jj < 3; ++jj) {
            int o = jj * 128 + lane * 2;
            uint v = *(const uint*)(row + r * 384 + o);
            float x0 = bf2f((ushort)(v & 0xffffu));
            float x1 = bf2f((ushort)(v >> 16));
#pragma unroll
            for (int t6 = 0; t6 < 6; ++t6)
                acc[r * 6 + t6] += x0 * qv[t6][o] + x1 * qv[t6][o + 1];
        }
    }
#pragma unroll
    for (int j = 0; j < 24; ++j) {
        float v = wave_sum(acc[j]);
        if (lane == 0) qkn[(long)n * 24 + j] = v;
    }
}

// ---------------- bf16 MFMA GEMM (2-phase double-buffered) ----------------
template<int OUT_BF16, int DUAL, int PARTIAL, int QK>
__global__ __launch_bounds__(256, 5)
void gemm_bf16(const ushort* __restrict__ A, const ushort* __restrict__ Bt,
               void* __restrict__ Cp, ushort* __restrict__ C2,
               const float* __restrict__ bias,
               int M, int K, int ldc, int nbn, int nwg, int nbase, int Ks,
               float* __restrict__ qkn, const float* __restrict__ qb, int qkcol) {
    __shared__ ushort lA[2][128 * 32];
    __shared__ ushort lB[2][128 * 32];
    const int t = threadIdx.x;
    const int lane = t & 63;
    const int wid = t >> 6;

    int b = blockIdx.x;
    int q8 = nwg >> 3, r8 = nwg & 7;
    int xcd = b & 7, loc = b >> 3;
    int tt = (xcd < r8 ? xcd * (q8 + 1) : r8 * (q8 + 1) + (xcd - r8) * q8) + loc;
    const int slice = tt / nbase;
    const int tile = tt % nbase;
    const int kbase = slice * Ks;
    const int bm = (tile / nbn) * 128;
    const int bn = (tile % nbn) * 128;

    const int wr = (wid >> 1) * 64;
    const int wc = (wid & 1) * 64;

    f32x4 acc[4][4];
#pragma unroll
    for (int m = 0; m < 4; ++m)
#pragma unroll
        for (int nn = 0; nn < 4; ++nn) acc[m][nn] = (f32x4){0.f, 0.f, 0.f, 0.f};

    const int sr = t >> 2;
    const int sk = (((t & 3) ^ ((t >> 3) & 3)) * 8);
    long ar0 = bm + sr;      if (ar0 > M - 1) ar0 = M - 1;
    long ar1 = bm + sr + 64; if (ar1 > M - 1) ar1 = M - 1;
    const ushort* gA0 = A + ar0 * K + sk + kbase;
    const ushort* gA1 = A + ar1 * K + sk + kbase;
    const ushort* gB0 = Bt + (long)(bn + sr) * K + sk + kbase;
    const ushort* gB1 = Bt + (long)(bn + sr + 64) * K + sk + kbase;

    const int frow = lane & 15;
    const int pc8 = (((lane >> 4) ^ ((lane >> 1) & 3)) * 8);

    GLD_LDS(gA0, &lA[0][t * 8]);
    GLD_LDS(gA1, &lA[0][t * 8 + 64 * 32]);
    GLD_LDS(gB0, &lB[0][t * 8]);
    GLD_LDS(gB1, &lB[0][t * 8 + 64 * 32]);
    __syncthreads();

    int cur = 0;
    for (int k0 = 0; k0 < Ks; k0 += 32) {
        if (k0 + 32 < Ks) {
            int nb = cur ^ 1, kn = k0 + 32;
            GLD_LDS(gA0 + kn, &lA[nb][t * 8]);
            GLD_LDS(gA1 + kn, &lA[nb][t * 8 + 64 * 32]);
            GLD_LDS(gB0 + kn, &lB[nb][t * 8]);
            GLD_LDS(gB1 + kn, &lB[nb][t * 8 + 64 * 32]);
        }
        bf16x8 af[4], bff[4];
#pragma unroll
        for (int m = 0; m < 4; ++m)
            af[m] = *(const bf16x8*)&lA[cur][(wr + m * 16 + frow) * 32 + pc8];
#pragma unroll
        for (int nn = 0; nn < 4; ++nn)
            bff[nn] = *(const bf16x8*)&lB[cur][(wc + nn * 16 + frow) * 32 + pc8];
#pragma unroll
        for (int m = 0; m < 4; ++m)
#pragma unroll
            for (int nn = 0; nn < 4; ++nn)
                acc[m][nn] = __builtin_amdgcn_mfma_f32_16x16x32_bf16(af[m], bff[nn], acc[m][nn], 0, 0, 0);
        __syncthreads();
        cur ^= 1;
    }

    const int crow = (lane >> 4) * 4;
    const int ccol = lane & 15;
#pragma unroll
    for (int m = 0; m < 4; ++m) {
#pragma unroll
        for (int nn = 0; nn < 4; ++nn) {
            int col = bn + wc + nn * 16 + ccol;
#pragma unroll
            for (int r = 0; r < 4; ++r) {
                int row = bm + wr + m * 16 + crow + r;
                if (row < M) {
                    float v = acc[m][nn][r];
                    if (QK && col >= qkcol) {
                        int qc = col - qkcol;
                        if (qc < 24) qkn[(long)row * 24 + qc] = v + (qb ? qb[qc] : 0.f);
                    } else {
                        if (!PARTIAL && bias) v += bias[col];
                        if (PARTIAL) {
                            ((float*)Cp)[(size_t)slice * M * ldc + (long)row * ldc + col] = v;
                        } else {
                            if (OUT_BF16) ((ushort*)Cp)[(long)row * ldc + col] = f2bf(v);
                            else          ((float*)Cp)[(long)row * ldc + col] = v;
                            if (DUAL)     C2[(long)row * ldc + col] = f2bf(v);
                        }
                    }
                }
            }
        }
    }
}

// ---------------- split-K reduce + fused qk for layer 2 ----------------
__global__ __launch_bounds__(256)
void reduce3qk_kernel(const float* __restrict__ P, const float* __restrict__ bf2,
                      const float* __restrict__ Wqk2,
                      float* __restrict__ outf, ushort* __restrict__ outb,
                      float* __restrict__ qkn, int M) {
    const int wid = threadIdx.x >> 6, lane = threadIdx.x & 63;
    const int n = blockIdx.x * 4 + wid;
    if (n >= M) return;
    long off = (long)n * 256 + lane * 4;
    const long stride = (long)M * 256;
    float4 a = *(const float4*)(P + off);
    float4 b = *(const float4*)(P + stride + off);
    float4 c = *(const float4*)(P + 2 * stride + off);
    float4 bs = *(const float4*)(bf2 + lane * 4);
    float rr[4] = { a.x + b.x + c.x + bs.x, a.y + b.y + c.y + bs.y,
                    a.z + b.z + c.z + bs.z, a.w + b.w + c.w + bs.w };
    float4 r4 = { rr[0], rr[1], rr[2], rr[3] };
    *(float4*)(outf + off) = r4;
    ushort4 o4 = { f2bf(rr[0]), f2bf(rr[1]), f2bf(rr[2]), f2bf(rr[3]) };
    *(ushort4*)(outb + off) = o4;
    float acc[24];
#pragma unroll
    for (int j = 0; j < 24; ++j) acc[j] = 0.f;
#pragma unroll
    for (int i = 0; i < 4; ++i) {
        const float* wr = Wqk2 + (long)(lane * 4 + i) * 24;
        float hv = rr[i];
#pragma unroll
        for (int j = 0; j < 24; ++j) acc[j] += hv * wr[j];
    }
#pragma unroll
    for (int j = 0; j < 24; ++j) {
        float v = wave_sum(acc[j]);
        if (lane == 0) qkn[(long)n * 24 + j] = v;
    }
}

// ================= attention (wave-per-node, no-max softmax, 4-slot pipelined gather) =================
__global__ __launch_bounds__(256)
void attn_kernel(const float* __restrict__ qkn, const ushort* __restrict__ xW,
                 const float* __restrict__ ae, const int* __restrict__ offs,
                 const int* __restrict__ csr, const int* __restrict__ srcv,
                 const int* __restrict__ etv, const float* __restrict__ bias,
                 ushort* __restrict__ out, int N, int ldx) {
    __shared__ float4 pk_sh[4][64];
    __shared__ float red[4][384];
    const int wid = threadIdx.x >> 6, lane = threadIdx.x & 63;
    const int n = blockIdx.x * 4 + wid;
    if (n >= N) return;
    const int e0 = offs[n];
    const int deg = offs[n + 1] - e0;
    const float* qd = qkn + (long)n * 24;

    float acc[6] = {0.f, 0.f, 0.f, 0.f, 0.f, 0.f};
    float ps0 = 0.f, ps1 = 0.f, ps2 = 0.f;

    for (int base = 0; base < deg; base += 64) {
        int cnt2 = deg - base; if (cnt2 > 64) cnt2 = 64;
        if (lane < cnt2) {
            int eid = csr[e0 + base + lane];
            int s_ = srcv[eid], t_ = etv[eid];
            const float* qs = qkn + (long)s_ * 24 + t_ * 6;
            const float* a3 = ae + (long)eid * 3;
            float v0 = qd[t_ * 6 + 0] + qs[3] + a3[0];
            float v1 = qd[t_ * 6 + 1] + qs[4] + a3[1];
            float v2 = qd[t_ * 6 + 2] + qs[5] + a3[2];
            v0 = v0 > 0.f ? v0 : 0.2f * v0;
            v1 = v1 > 0.f ? v1 : 0.2f * v1;
            v2 = v2 > 0.f ? v2 : 0.2f * v2;
            float p0 = __expf(v0), p1 = __expf(v1), p2 = __expf(v2);
            pk_sh[wid][lane] = make_float4(p0, p1, p2, __int_as_float((s_ << 2) | t_));
            ps0 += p0; ps1 += p1; ps2 += p2;
        }
        wave_sync();
        float4 pk0 = {0,0,0,0}, pk1 = {0,0,0,0}, pk2 = {0,0,0,0}, pk3 = {0,0,0,0};
        uint a0 = 0, b0 = 0, c0 = 0, a1 = 0, b1 = 0, c1 = 0;
        uint a2 = 0, b2 = 0, c2 = 0, a3 = 0, b3 = 0, c3 = 0;
#define LDE(S, J) { pk##S = pk_sh[wid][J]; int pk_ = __float_as_int(pk##S.w); \
    const uint* xr = (const uint*)(xW + (long)(pk_ >> 2) * ldx + (pk_ & 3) * 384); \
    a##S = xr[lane]; b##S = xr[lane + 64]; c##S = xr[lane + 128]; }
#define ACCE(S) { \
    acc[0] += pk##S.x * bf2f((ushort)(a##S & 0xffffu)); \
    acc[1] += pk##S.x * bf2f((ushort)(a##S >> 16)); \
    acc[2] += pk##S.y * bf2f((ushort)(b##S & 0xffffu)); \
    acc[3] += pk##S.y * bf2f((ushort)(b##S >> 16)); \
    acc[4] += pk##S.z * bf2f((ushort)(c##S & 0xffffu)); \
    acc[5] += pk##S.z * bf2f((ushort)(c##S >> 16)); }
        if (0 < cnt2) LDE(0, 0);
        if (1 < cnt2) LDE(1, 1);
        if (2 < cnt2) LDE(2, 2);
        if (3 < cnt2) LDE(3, 3);
        for (int j = 0; j < cnt2; j += 4) {
            { ACCE(0); if (j + 4 < cnt2) LDE(0, j + 4); }
            if (j + 1 < cnt2) { ACCE(1); if (j + 5 < cnt2) LDE(1, j + 5); }
            if (j + 2 < cnt2) { ACCE(2); if (j + 6 < cnt2) LDE(2, j + 6); }
            if (j + 3 < cnt2) { ACCE(3); if (j + 7 < cnt2) LDE(3, j + 7); }
        }
#undef LDE
#undef ACCE
        wave_sync();
    }
    ps0 = wave_sum(ps0); ps1 = wave_sum(ps1); ps2 = wave_sum(ps2);
    float i0 = 1.f / fmaxf(ps0, 1e-16f);
    float i1 = 1.f / fmaxf(ps1, 1e-16f);
    float i2 = 1.f / fmaxf(ps2, 1e-16f);
    red[wid][2 * lane]           = acc[0] * i0;
    red[wid][2 * lane + 1]       = acc[1] * i0;
    red[wid][128 + 2 * lane]     = acc[2] * i1;
    red[wid][128 + 2 * lane + 1] = acc[3] * i1;
    red[wid][256 + 2 * lane]     = acc[4] * i2;
    red[wid][256 + 2 * lane + 1] = acc[5] * i2;
    wave_sync();
    for (int o = lane; o < 128; o += 64) {
        float v = (red[wid][o] + red[wid][128 + o] + red[wid][256 + o]) * (1.f / 3.f) + bias[o];
        out[(long)n * 128 + o] = f2bf(v);
    }
}

// layer 2: Z-accumulation (wave-per-node, no-max softmax, 4-slot pipelined gather)
__global__ __launch_bounds__(256)
void attn2_kernel(const float* __restrict__ qkn, const ushort* __restrict__ hbf,
                  const float* __restrict__ ae, const int* __restrict__ offs,
                  const int* __restrict__ csr, const int* __restrict__ srcv,
                  const int* __restrict__ etv, ushort* __restrict__ Z, int N) {
    __shared__ float4 pk_sh[4][64];
    const int wid = threadIdx.x >> 6, lane = threadIdx.x & 63;
    const int n = blockIdx.x * 4 + wid;
    if (n >= N) return;
    const int e0 = offs[n];
    const int deg = offs[n + 1] - e0;
    const float* qd = qkn + (long)n * 24;

    float acc[48];
#pragma unroll
    for (int i = 0; i < 48; ++i) acc[i] = 0.f;
    float ps0 = 0.f, ps1 = 0.f, ps2 = 0.f;

    for (int base = 0; base < deg; base += 64) {
        int cnt2 = deg - base; if (cnt2 > 64) cnt2 = 64;
        if (lane < cnt2) {
            int eid = csr[e0 + base + lane];
            int s_ = srcv[eid], t_ = etv[eid];
            const float* qs = qkn + (long)s_ * 24 + t_ * 6;
            const float* a3 = ae + (long)eid * 3;
            float v0 = qd[t_ * 6 + 0] + qs[3] + a3[0];
            float v1 = qd[t_ * 6 + 1] + qs[4] + a3[1];
            float v2 = qd[t_ * 6 + 2] + qs[5] + a3[2];
            v0 = v0 > 0.f ? v0 : 0.2f * v0;
            v1 = v1 > 0.f ? v1 : 0.2f * v1;
            v2 = v2 > 0.f ? v2 : 0.2f * v2;
            float p0 = __expf(v0), p1 = __expf(v1), p2 = __expf(v2);
            pk_sh[wid][lane] = make_float4(p0, p1, p2, __int_as_float((s_ << 2) | t_));
            ps0 += p0; ps1 += p1; ps2 += p2;
        }
        wave_sync();
        float4 pk0 = {0,0,0,0}, pk1 = {0,0,0,0}, pk2 = {0,0,0,0}, pk3 = {0,0,0,0};
        uint2 v0_ = {0,0}, v1_ = {0,0}, v2_ = {0,0}, v3_ = {0,0};
#define LDE2(S, J) { pk##S = pk_sh[wid][J]; \
    v##S##_ = *(const uint2*)(hbf + ((long)(__float_as_int(pk##S.w) >> 2)) * 256 + lane * 4); }
#define UPDR(R) { \
    acc[(R)*4+0] += px * x0; acc[(R)*4+1] += px * x1; acc[(R)*4+2] += px * x2; acc[(R)*4+3] += px * x3; \
    acc[16+(R)*4+0] += py * x0; acc[16+(R)*4+1] += py * x1; acc[16+(R)*4+2] += py * x2; acc[16+(R)*4+3] += py * x3; \
    acc[32+(R)*4+0] += pz * x0; acc[32+(R)*4+1] += pz * x1; acc[32+(R)*4+2] += pz * x2; acc[32+(R)*4+3] += pz * x3; }
#define ACC2(S) { int r_ = __float_as_int(pk##S.w) & 3; \
    float x0 = bf2f((ushort)(v##S##_.x & 0xffffu)), x1 = bf2f((ushort)(v##S##_.x >> 16)); \
    float x2 = bf2f((ushort)(v##S##_.y & 0xffffu)), x3 = bf2f((ushort)(v##S##_.y >> 16)); \
    float px = pk##S.x, py = pk##S.y, pz = pk##S.z; \
    if (r_ == 0) UPDR(0) else if (r_ == 1) UPDR(1) else if (r_ == 2) UPDR(2) else UPDR(3) }
        if (0 < cnt2) LDE2(0, 0);
        if (1 < cnt2) LDE2(1, 1);
        if (2 < cnt2) LDE2(2, 2);
        if (3 < cnt2) LDE2(3, 3);
        for (int j = 0; j < cnt2; j += 4) {
            { ACC2(0); if (j + 4 < cnt2) LDE2(0, j + 4); }
            if (j + 1 < cnt2) { ACC2(1); if (j + 5 < cnt2) LDE2(1, j + 5); }
            if (j + 2 < cnt2) { ACC2(2); if (j + 6 < cnt2) LDE2(2, j + 6); }
            if (j + 3 < cnt2) { ACC2(3); if (j + 7 < cnt2) LDE2(3, j + 7); }
        }
#undef LDE2
#undef UPDR
#undef ACC2
        wave_sync();
    }
    ps0 = wave_sum(ps0); ps1 = wave_sum(ps1); ps2 = wave_sum(ps2);
    float inv0 = 1.f / fmaxf(ps0, 1e-16f);
    float inv1 = 1.f / fmaxf(ps1, 1e-16f);
    float inv2 = 1.f / fmaxf(ps2, 1e-16f);
    ushort* zr = Z + (long)n * 3072 + lane * 4;
#pragma unroll
    for (int h = 0; h < 3; ++h) {
        float iv = (h == 0) ? inv0 : (h == 1 ? inv1 : inv2);
#pragma unroll
        for (int r = 0; r < 4; ++r) {
            const float* a4 = acc + h * 16 + r * 4;
            ushort4 o4 = { f2bf(a4[0] * iv), f2bf(a4[1] * iv),
                           f2bf(a4[2] * iv), f2bf(a4[3] * iv) };
            *(ushort4*)(zr + h * 1024 + r * 256) = o4;
        }
    }
}

// ---------------- final: hole-node softmax ----------------
__global__ void softmax_kernel(const float* __restrict__ h, const int* __restrict__ hole,
                               float* __restrict__ out, int B) {
    int b = blockIdx.x;
    int t = threadIdx.x;
    int lane = t & 63, wid = t >> 6;
    __shared__ float sm[4];
    __shared__ float ss[4];
    int row = hole[b];
    float v = h[(long)row * 256 + t];
    float m = v;
#pragma unroll
    for (int d = 32; d >= 1; d >>= 1) m = fmaxf(m, __shfl_xor(m, d));
    if (lane == 0) sm[wid] = m;
    __syncthreads();
    m = fmaxf(fmaxf(sm[0], sm[1]), fmaxf(sm[2], sm[3]));
    float ex = __expf(v - m);
    float s = ex;
#pragma unroll
    for (int d = 32; d >= 1; d >>= 1) s += __shfl_xor(s, d);
    if (lane == 0) ss[wid] = s;
    __syncthreads();
    s = ss[0] + ss[1] + ss[2] + ss[3];
    out[(long)b * 256 + t] = ex / s;
}

// ---------------- host ----------------
extern "C" void kernel_launch(void* const* d_in, const int* in_sizes, int n_in,
                              void* d_out, int out_size, void* d_ws, size_t ws_size,
                              hipStream_t stream) {
    const float* x   = (const float*)d_in[0];
    const int*   ei  = (const int*)d_in[1];
    const int*   ety = (const int*)d_in[2];
    const float* ea  = (const float*)d_in[3];
    const int*   bat = (const int*)d_in[4];

    const int N = in_sizes[0] / 768;
    const int E = in_sizes[2];
    const int B = out_size / 256;

    static const int CIN[4]  = {768, 256, 256, 256};
    static const int COUT[4] = {128, 384, 128, 128};
    static const int NCC[4]  = {1536, 4608, 1536, 1536};

    const float *Wp[4], *qp[4], *kp[4], *lep[4], *ep[4], *bp[4], *lwp[4], *lbp[4];
    for (int l = 0; l < 4; ++l) {
        Wp[l]  = (const float*)d_in[5 + 6 * l];
        qp[l]  = (const float*)d_in[6 + 6 * l];
        kp[l]  = (const float*)d_in[7 + 6 * l];
        lep[l] = (const float*)d_in[8 + 6 * l];
        ep[l]  = (const float*)d_in[9 + 6 * l];
        bp[l]  = (const float*)d_in[10 + 6 * l];
        lwp[l] = (const float*)d_in[29 + 2 * l];
        lbp[l] = (const float*)d_in[30 + 2 * l];
    }

    char* ws = (char*)d_ws;
    size_t pos = 0;
    auto carve = [&](size_t bytes) -> char* {
        char* r = ws + pos;
        pos += (bytes + 255) & ~(size_t)255;
        return r;
    };
    ushort *Wt[4], *lwT[4];
    float* Wqk[4];
    for (int l = 0; l < 4; ++l) Wt[l]  = (ushort*)carve(l == 1 ? 0 : (size_t)2 * NCC[l] * CIN[l]);
    for (int l = 0; l < 4; ++l) lwT[l] = (ushort*)carve((size_t)2 * 384 * COUT[l]);
    for (int l = 0; l < 4; ++l) Wqk[l] = (float*)carve((size_t)4 * 24 * CIN[l]);
    float*  gbuf  = (float*)carve(4 * 24 * 4);
    float*  aeb   = (float*)carve((size_t)4 * E * 3 * 4);
    float*  qkn   = (float*)carve((size_t)N * 24 * 4);
    float*  qb1   = (float*)carve(24 * 4);
    float*  qb3   = (float*)carve(24 * 4);
    ushort* hbf   = (ushort*)carve((size_t)N * 768 * 2);
    ushort* xWb   = (ushort*)carve((size_t)N * 1536 * 2);   // also split-K fp32 partials
    ushort* Zb    = (ushort*)carve((size_t)N * 3072 * 2);
    ushort* A2    = (ushort*)carve((size_t)3072 * 384 * 2);
    ushort* W2T   = (ushort*)carve((size_t)256 * 3072 * 2);
    float*  bf2   = (float*)carve(256 * 4);
    ushort* convbf= (ushort*)carve((size_t)N * 384 * 2);
    float*  hbuf  = (float*)carve((size_t)N * 256 * 4);
    int* cnt  = (int*)carve((size_t)N * 4);
    int* cur  = (int*)carve((size_t)N * 4);
    int* offs = (int*)carve((size_t)(N + 1) * 4);
    int* csr  = (int*)carve((size_t)E * 4);
    int* hole = (int*)carve((size_t)B * 4);

    hipMemsetAsync(cnt, 0, (size_t)((char*)cur - (char*)cnt) + (size_t)N * 4, stream);
    hipMemsetAsync(hole, 0x7f, (size_t)B * 4, stream);

    const int* dst = ei + E;
    int nbEH = ((E > N ? E : N) + 255) / 256;
    deg_hole_kernel<<<nbEH, 256, 0, stream>>>(dst, cnt, bat, hole, E, N);
    scan_kernel<<<1, 1024, 0, stream>>>(cnt, offs, N);
    fill_kernel<<<(E + 255) / 256, 256, 0, stream>>>(dst, offs, cur, csr, E);

    PrepSArgs psa = { Wp[1], Wp[2], Wp[3], qp[1], qp[2], qp[3],
                      kp[1], kp[2], kp[3], Wqk[1], Wqk[2], Wqk[3],
                      lep[0], lep[1], lep[2], lep[3], ep[0], ep[1], ep[2], ep[3],
                      gbuf, bp[1], lwp[1], lbp[1], bf2 };
    preps_kernel<<<(3424 + 3) / 4, 256, 0, stream>>>(psa);

    long nCast = (long)N * 768;
    int nbCast = (int)((nCast / 4 + 255) / 256);
    int nbAe = (E + 255) / 256;
    PrepWArgs pw = { x, Wp[0], Wp[2], Wp[3], lwp[0], lwp[1], lwp[2], lwp[3], Wp[1],
                     hbf, Wt[0], Wt[2], Wt[3], lwT[0], lwT[1], lwT[2], lwT[3], A2,
                     ea, gbuf, aeb, Wqk[1], Wqk[3], lbp[0], lbp[2], qb1, qb3 };
    prepw_kernel<<<nbCast + nbAe + 4628, 256, 0, stream>>>(pw, nbCast, nCast, E, nbAe);

    gemm_bf16<1, 0, 0, 0><<<48, 256, 0, stream>>>(lwT[1], A2, (void*)W2T, nullptr, nullptr,
                                                  256, 384, 3072, 24, 48, 48, 384,
                                                  nullptr, nullptr, 0);

    const int nbm = (N + 127) / 128;
    for (int l = 0; l < 4; ++l) {
        if (l == 1) {
            attn2_kernel<<<(N + 3) / 4, 256, 0, stream>>>(qkn, hbf, aeb + (size_t)l * E * 3,
                                                          offs, csr, ei, ety, Zb, N);
            int nbase = nbm * 2, nwgS = nbase * 3;
            gemm_bf16<0, 0, 1, 0><<<nwgS, 256, 0, stream>>>(Zb, W2T, (void*)xWb, nullptr, nullptr,
                                                            N, 3072, 256, 2, nwgS, nbase, 1024,
                                                            nullptr, nullptr, 0);
            reduce3qk_kernel<<<(N + 3) / 4, 256, 0, stream>>>((const float*)xWb, bf2, Wqk[2],
                                                              hbuf, hbf, qkn, N);
        } else {
            int nbn1 = NCC[l] / 128, nwg1 = nbm * nbn1;
            gemm_bf16<1, 0, 0, 0><<<nwg1, 256, 0, stream>>>(hbf, Wt[l], (void*)xWb, nullptr,
                                                            nullptr, N, CIN[l], NCC[l], nbn1,
                                                            nwg1, nwg1, CIN[l],
                                                            nullptr, nullptr, 0);
            if (l == 0)
                qkx_kernel<<<(N + 3) / 4, 256, 0, stream>>>(xWb, qp[0], kp[0], qkn, N);
            attn_kernel<<<(N + 3) / 4, 256, 0, stream>>>(qkn, xWb, aeb + (size_t)l * E * 3,
                                                         offs, csr, ei, ety, bp[l], convbf, N, 1536);
            if (l == 3) {
                int nwg2 = nbm * 2;
                gemm_bf16<0, 0, 0, 0><<<nwg2, 256, 0, stream>>>(convbf, lwT[3], (void*)hbuf, nullptr,
                                                                lbp[3], N, 128, 256, 2, nwg2, nwg2, 128,
                                                                nullptr, nullptr, 0);
            } else {
                float* qbp = (l == 0) ? qb1 : qb3;
                int nwg2 = nbm * 3;
                gemm_bf16<0, 1, 0, 1><<<nwg2, 256, 0, stream>>>(convbf, lwT[l], (void*)hbuf, hbf,
                                                                lbp[l], N, 128, 256, 3, nwg2, nwg2, 128,
                                                                qkn, qbp, 256);
            }
        }
    }
    softmax_kernel<<<B, 256, 0, stream>>>(hbuf, hole, (float*)d_out, B);
}

// Round 20
// 418.856 us; speedup vs baseline: 2.0988x; 1.0748x over previous
//
#include <hip/hip_runtime.h>

typedef unsigned int uint;
typedef unsigned short ushort;
typedef __attribute__((ext_vector_type(8))) short bf16x8;
typedef __attribute__((ext_vector_type(4))) float f32x4;

#define GLD_LDS(g, l) __builtin_amdgcn_global_load_lds( \
    (const __attribute__((address_space(1))) void*)(g), \
    (__attribute__((address_space(3))) void*)(l), 16, 0, 0)

__device__ __forceinline__ ushort f2bf(float f) {
    uint u = __builtin_bit_cast(uint, f);
    u += 0x7fffu + ((u >> 16) & 1u);
    return (ushort)(u >> 16);
}
__device__ __forceinline__ float bf2f(ushort s) {
    uint u = ((uint)s) << 16;
    return __builtin_bit_cast(float, u);
}
__device__ __forceinline__ void wave_sync() {
    asm volatile("s_waitcnt lgkmcnt(0)" ::: "memory");
}
__device__ __forceinline__ float wave_sum(float v) {
#pragma unroll
    for (int d = 32; d >= 1; d >>= 1) v += __shfl_xor(v, d);
    return v;
}

// ---------------- CSR build ----------------
__global__ void deg_kernel(const int* __restrict__ dst, int* __restrict__ cnt, int E) {
    int e = blockIdx.x * 256 + threadIdx.x;
    if (e < E) atomicAdd(&cnt[dst[e]], 1);
}

__global__ void scan_kernel(const int* __restrict__ cnt, int* __restrict__ offs, int n) {
    __shared__ int part[1024];
    const int t = threadIdx.x;
    const int strip = (n + 1023) / 1024;
    int s = 0;
    for (int i = 0; i < strip; ++i) {
        int idx = t * strip + i;
        if (idx < n) s += cnt[idx];
    }
    part[t] = s;
    __syncthreads();
    for (int d = 1; d < 1024; d <<= 1) {
        int v = (t >= d) ? part[t - d] : 0;
        __syncthreads();
        part[t] += v;
        __syncthreads();
    }
    int run = (t == 0) ? 0 : part[t - 1];
    for (int i = 0; i < strip; ++i) {
        int idx = t * strip + i;
        if (idx < n) { offs[idx] = run; run += cnt[idx]; }
    }
    if (t == 1023) offs[n] = part[1023];
}

__global__ void fill_kernel(const int* __restrict__ dst, const int* __restrict__ offs,
                            int* __restrict__ cur, int* __restrict__ csr, int E) {
    int e = blockIdx.x * 256 + threadIdx.x;
    if (e < E) {
        int d = dst[e];
        int p = offs[d] + atomicAdd(&cur[d], 1);
        csr[p] = e;
    }
}

// ---------------- fused small reductions (wave-granular regions) ----------------
struct PrepSArgs {
    const float *W1, *W2, *W3, *q1, *q2, *q3, *k1, *k2, *k3;
    float *Wqk1, *Wqk2, *Wqk3;
    const float *le0, *le1, *le2, *le3, *e0, *e1, *e2, *e3;
    float* g;
    const float *b2, *lw2l, *lb2;
    float* bf2;
};

__device__ __forceinline__ void wqk_body(const float* W, const float* q, const float* k,
                                         float* Wqk, int cin, int ho, int i, int lane) {
    int c = i >> 2, r = i & 3;
    const float* wrow = W + ((long)r * cin + c) * ho;
    float sq0 = 0.f, sq1 = 0.f, sq2 = 0.f, sk0 = 0.f, sk1 = 0.f, sk2 = 0.f;
    for (int o = lane; o < ho; o += 64) {
        float w = wrow[o];
        sq0 += w * q[(long)o * 3 + 0];
        sq1 += w * q[(long)o * 3 + 1];
        sq2 += w * q[(long)o * 3 + 2];
        sk0 += w * k[(long)o * 3 + 0];
        sk1 += w * k[(long)o * 3 + 1];
        sk2 += w * k[(long)o * 3 + 2];
    }
    sq0 = wave_sum(sq0); sq1 = wave_sum(sq1); sq2 = wave_sum(sq2);
    sk0 = wave_sum(sk0); sk1 = wave_sum(sk1); sk2 = wave_sum(sk2);
    if (lane == 0) {
        float* w6 = Wqk + (long)c * 24 + r * 6;
        w6[0] = sq0; w6[1] = sq1; w6[2] = sq2;
        w6[3] = sk0; w6[4] = sk1; w6[5] = sk2;
    }
}

__global__ __launch_bounds__(256)
void preps_kernel(PrepSArgs a) {
    const int wid = threadIdx.x >> 6, lane = threadIdx.x & 63;
    int w = blockIdx.x * 4 + wid;
    if (w < 96) {
        int l = w / 24, j = w % 24;
        int d = j / 3, h = j % 3;
        const float* le = (l == 0) ? a.le0 : (l == 1 ? a.le1 : (l == 2 ? a.le2 : a.le3));
        const float* e  = (l == 0) ? a.e0  : (l == 1 ? a.e1  : (l == 2 ? a.e2  : a.e3));
        int ho = (l == 1) ? 1152 : 384;
        float s = 0.f;
        for (int o = lane; o < ho; o += 64) s += le[(long)d * ho + o] * e[(long)o * 3 + h];
        s = wave_sum(s);
        if (lane == 0) a.g[l * 24 + j] = s;
        return;
    }
    w -= 96;
    if (w < 1024) { wqk_body(a.W1, a.q1, a.k1, a.Wqk1, 256, 1152, w, lane); return; }
    w -= 1024;
    if (w < 1024) { wqk_body(a.W2, a.q2, a.k2, a.Wqk2, 256, 384, w, lane); return; }
    w -= 1024;
    if (w < 1024) { wqk_body(a.W3, a.q3, a.k3, a.Wqk3, 256, 384, w, lane); return; }
    w -= 1024;
    if (w < 256) {
        float s = 0.f;
        for (int o = lane; o < 384; o += 64) s += a.b2[o] * a.lw2l[(long)o * 256 + w];
        s = wave_sum(s);
        if (lane == 0) a.bf2[w] = s + a.lb2[w];
    }
}

// ---------------- fused weight prep + ae + qk-fold weights (regions) ----------------
struct PrepWArgs {
    const float *x, *W0, *W2, *W3, *lw0, *lw1, *lw2, *lw3, *W1;
    ushort *hbf, *Wt0, *Wt2, *Wt3, *lwT0, *lwT1, *lwT2, *lwT3, *A2;
    const float *ea, *g;
    float* aeb;
    const float *Wqk1, *Wqk3, *lb0, *lb2;
    float *qb1, *qb3;
};

__device__ __forceinline__ void trLw_body(const float* lw, ushort* lwT, int cout_in, long idx) {
    int o = (int)(idx / cout_in);
    int c = (int)(idx % cout_in);
    lwT[idx] = f2bf(lw[(long)c * 256 + o]);
}

__device__ __forceinline__ void trWT_body(const float* W, ushort* Wt, int cin, int ho,
                                          int bt, int t, float (*tile)[65]) {
    const int tpo = ho / 64;
    const int tpc = cin / 64;
    const int per_r = tpc * tpo;
    int r = bt / per_r, rem = bt % per_r;
    int c0 = (rem / tpo) * 64, o0 = (rem % tpo) * 64;
    const int ti = t >> 6, tj = t & 63;
#pragma unroll
    for (int p = 0; p < 16; ++p) {
        int c = c0 + ti + 4 * p;
        tile[ti + 4 * p][tj] = W[((long)r * cin + c) * ho + o0 + tj];
    }
    __syncthreads();
#pragma unroll
    for (int p = 0; p < 16; ++p) {
        int o = o0 + ti + 4 * p;
        Wt[((long)(r * ho + o)) * cin + c0 + tj] = f2bf(tile[tj][ti + 4 * p]);
    }
}

__global__ __launch_bounds__(256)
void prepw_kernel(PrepWArgs a, int nbCast, long nCast, int E, int nbAe) {
    __shared__ float tile[64][65];
    int b = blockIdx.x;
    const int t = threadIdx.x;
    if (b < nbCast) {
        long i = ((long)b * 256 + t) * 4;
        if (i + 4 <= nCast) {
            float4 v = *(const float4*)(a.x + i);
            ushort4 o4 = { f2bf(v.x), f2bf(v.y), f2bf(v.z), f2bf(v.w) };
            *(ushort4*)(a.hbf + i) = o4;
        }
        return;
    }
    b -= nbCast;
    if (b < 288) { trWT_body(a.W0, a.Wt0, 768, 384, b, t, tile); return; }
    b -= 288;
    if (b < 96)  { trWT_body(a.W2, a.Wt2, 256, 384, b, t, tile); return; }
    b -= 96;
    if (b < 96)  { trWT_body(a.W3, a.Wt3, 256, 384, b, t, tile); return; }
    b -= 96;
    if (b < 128)  { trLw_body(a.lw0, a.lwT0, 128, (long)b * 256 + t); return; }
    b -= 128;
    if (b < 384)  { trLw_body(a.lw1, a.lwT1, 384, (long)b * 256 + t); return; }
    b -= 384;
    if (b < 128)  { trLw_body(a.lw2, a.lwT2, 128, (long)b * 256 + t); return; }
    b -= 128;
    if (b < 128)  { trLw_body(a.lw3, a.lwT3, 128, (long)b * 256 + t); return; }
    b -= 128;
    if (b < 1728) {
        long idx = (long)b * 256 + t;
        int j = (int)(idx / 384), o = (int)(idx % 384);
        int h = j >> 10, rc = j & 1023;
        int r = rc >> 8, c = rc & 255;
        a.A2[idx] = f2bf(a.W1[((long)(r * 256 + c)) * 1152 + h * 384 + o] * (1.f / 3.f));
        return;
    }
    b -= 1728;
    if (b < nbAe) {
        int e = b * 256 + t;
        if (e >= E) return;
        float av[8];
#pragma unroll
        for (int d = 0; d < 8; ++d) av[d] = a.ea[(long)e * 8 + d];
#pragma unroll
        for (int l = 0; l < 4; ++l) {
#pragma unroll
            for (int h = 0; h < 3; ++h) {
                float s = 0.f;
#pragma unroll
                for (int d = 0; d < 8; ++d) s += av[d] * a.g[l * 24 + d * 3 + h];
                a.aeb[((size_t)l * E + e) * 3 + h] = s;
            }
        }
        return;
    }
    b -= nbAe;
    const int wid = t >> 6, lane = t & 63;
    if (b < 768) {
        int w = b * 4 + wid;
        int c = w / 24, j = w % 24;
        float s = 0.f;
        for (int o = lane; o < 256; o += 64) s += a.lw0[(long)c * 256 + o] * a.Wqk1[(long)o * 24 + j];
        s = wave_sum(s);
        if (lane == 0) a.lwT0[(256 + j) * 128 + c] = f2bf(s);
        return;
    }
    b -= 768;
    if (b < 768) {
        int w = b * 4 + wid;
        int c = w / 24, j = w % 24;
        float s = 0.f;
        for (int o = lane; o < 256; o += 64) s += a.lw2[(long)c * 256 + o] * a.Wqk3[(long)o * 24 + j];
        s = wave_sum(s);
        if (lane == 0) a.lwT2[(256 + j) * 128 + c] = f2bf(s);
        return;
    }
    b -= 768;
    if (b < 6) {
        int w = b * 4 + wid;
        if (w < 24) {
            float s = 0.f;
            for (int o = lane; o < 256; o += 64) s += a.lb0[o] * a.Wqk1[(long)o * 24 + w];
            s = wave_sum(s);
            if (lane == 0) a.qb1[w] = s;
        }
        return;
    }
    b -= 6;
    if (b < 6) {
        int w = b * 4 + wid;
        if (w < 24) {
            float s = 0.f;
            for (int o = lane; o < 256; o += 64) s += a.lb2[o] * a.Wqk3[(long)o * 24 + w];
            s = wave_sum(s);
            if (lane == 0) a.qb3[w] = s;
        }
        return;
    }
    b -= 6;
    if (b < 52) { a.lwT0[280 * 128 + b * 256 + t] = 0; return; }
    b -= 52;
    a.lwT2[280 * 128 + b * 256 + t] = 0;
}

// ---------------- qkn for layer 0 from xWb ----------------
__global__ __launch_bounds__(256)
void qkx_kernel(const ushort* __restrict__ xW, const float* __restrict__ q0,
                const float* __restrict__ k0, float* __restrict__ qkn, int N) {
    __shared__ float qv[6][384];
    const int t = threadIdx.x, wid = t >> 6, lane = t & 63;
    for (int i = t; i < 384; i += 256) {
        qv[0][i] = q0[i * 3 + 0]; qv[1][i] = q0[i * 3 + 1]; qv[2][i] = q0[i * 3 + 2];
        qv[3][i] = k0[i * 3 + 0]; qv[4][i] = k0[i * 3 + 1]; qv[5][i] = k0[i * 3 + 2];
    }
    __syncthreads();
    const int n = blockIdx.x * 4 + wid;
    if (n >= N) return;
    const ushort* row = xW + (long)n * 1536;
    float acc[24];
#pragma unroll
    for (int j = 0; j < 24; ++j) acc[j] = 0.f;
#pragma unroll
    for (int r = 0; r < 4; ++r) {
#pragma unroll
        for (int jj = 0; jj < 3; ++jj) {
            int o = jj * 128 + lane * 2;
            uint v = *(const uint*)(row + r * 384 + o);
            float x0 = bf2f((ushort)(v & 0xffffu));
            float x1 = bf2f((ushort)(v >> 16));
#pragma unroll
            for (int t6 = 0; t6 < 6; ++t6)
                acc[r * 6 + t6] += x0 * qv[t6][o] + x1 * qv[t6][o + 1];
        }
    }
#pragma unroll
    for (int j = 0; j < 24; ++j) {
        float v = wave_sum(acc[j]);
        if (lane == 0) qkn[(long)n * 24 + j] = v;
    }
}

// ---------------- bf16 MFMA GEMM (2-phase double-buffered) ----------------
template<int OUT_BF16, int DUAL, int PARTIAL, int QK>
__global__ __launch_bounds__(256, 5)
void gemm_bf16(const ushort* __restrict__ A, const ushort* __restrict__ Bt,
               void* __restrict__ Cp, ushort* __restrict__ C2,
               const float* __restrict__ bias,
               int M, int K, int ldc, int nbn, int nwg, int nbase, int Ks,
               float* __restrict__ qkn, const float* __restrict__ qb, int qkcol) {
    __shared__ ushort lA[2][128 * 32];
    __shared__ ushort lB[2][128 * 32];
    const int t = threadIdx.x;
    const int lane = t & 63;
    const int wid = t >> 6;

    int b = blockIdx.x;
    int q8 = nwg >> 3, r8 = nwg & 7;
    int xcd = b & 7, loc = b >> 3;
    int tt = (xcd < r8 ? xcd * (q8 + 1) : r8 * (q8 + 1) + (xcd - r8) * q8) + loc;
    const int slice = tt / nbase;
    const int tile = tt % nbase;
    const int kbase = slice * Ks;
    const int bm = (tile / nbn) * 128;
    const int bn = (tile % nbn) * 128;

    const int wr = (wid >> 1) * 64;
    const int wc = (wid & 1) * 64;

    f32x4 acc[4][4];
#pragma unroll
    for (int m = 0; m < 4; ++m)
#pragma unroll
        for (int nn = 0; nn < 4; ++nn) acc[m][nn] = (f32x4){0.f, 0.f, 0.f, 0.f};

    const int sr = t >> 2;
    const int sk = (((t & 3) ^ ((t >> 3) & 3)) * 8);
    long ar0 = bm + sr;      if (ar0 > M - 1) ar0 = M - 1;
    long ar1 = bm + sr + 64; if (ar1 > M - 1) ar1 = M - 1;
    const ushort* gA0 = A + ar0 * K + sk + kbase;
    const ushort* gA1 = A + ar1 * K + sk + kbase;
    const ushort* gB0 = Bt + (long)(bn + sr) * K + sk + kbase;
    const ushort* gB1 = Bt + (long)(bn + sr + 64) * K + sk + kbase;

    const int frow = lane & 15;
    const int pc8 = (((lane >> 4) ^ ((lane >> 1) & 3)) * 8);

    GLD_LDS(gA0, &lA[0][t * 8]);
    GLD_LDS(gA1, &lA[0][t * 8 + 64 * 32]);
    GLD_LDS(gB0, &lB[0][t * 8]);
    GLD_LDS(gB1, &lB[0][t * 8 + 64 * 32]);
    __syncthreads();

    int cur = 0;
    for (int k0 = 0; k0 < Ks; k0 += 32) {
        if (k0 + 32 < Ks) {
            int nb = cur ^ 1, kn = k0 + 32;
            GLD_LDS(gA0 + kn, &lA[nb][t * 8]);
            GLD_LDS(gA1 + kn, &lA[nb][t * 8 + 64 * 32]);
            GLD_LDS(gB0 + kn, &lB[nb][t * 8]);
            GLD_LDS(gB1 + kn, &lB[nb][t * 8 + 64 * 32]);
        }
        bf16x8 af[4], bff[4];
#pragma unroll
        for (int m = 0; m < 4; ++m)
            af[m] = *(const bf16x8*)&lA[cur][(wr + m * 16 + frow) * 32 + pc8];
#pragma unroll
        for (int nn = 0; nn < 4; ++nn)
            bff[nn] = *(const bf16x8*)&lB[cur][(wc + nn * 16 + frow) * 32 + pc8];
#pragma unroll
        for (int m = 0; m < 4; ++m)
#pragma unroll
            for (int nn = 0; nn < 4; ++nn)
                acc[m][nn] = __builtin_amdgcn_mfma_f32_16x16x32_bf16(af[m], bff[nn], acc[m][nn], 0, 0, 0);
        __syncthreads();
        cur ^= 1;
    }

    const int crow = (lane >> 4) * 4;
    const int ccol = lane & 15;
#pragma unroll
    for (int m = 0; m < 4; ++m) {
#pragma unroll
        for (int nn = 0; nn < 4; ++nn) {
            int col = bn + wc + nn * 16 + ccol;
#pragma unroll
            for (int r = 0; r < 4; ++r) {
                int row = bm + wr + m * 16 + crow + r;
                if (row < M) {
                    float v = acc[m][nn][r];
                    if (QK && col >= qkcol) {
                        int qc = col - qkcol;
                        if (qc < 24) qkn[(long)row * 24 + qc] = v + (qb ? qb[qc] : 0.f);
                    } else {
                        if (!PARTIAL && bias) v += bias[col];
                        if (PARTIAL) {
                            ((float*)Cp)[(size_t)slice * M * ldc + (long)row * ldc + col] = v;
                        } else {
                            if (OUT_BF16) ((ushort*)Cp)[(long)row * ldc + col] = f2bf(v);
                            else          ((float*)Cp)[(long)row * ldc + col] = v;
                            if (DUAL)     C2[(long)row * ldc + col] = f2bf(v);
                        }
                    }
                }
            }
        }
    }
}

// ---------------- split-K reduce + fused qk for layer 2 ----------------
__global__ __launch_bounds__(256)
void reduce3qk_kernel(const float* __restrict__ P, const float* __restrict__ bf2,
                      const float* __restrict__ Wqk2,
                      float* __restrict__ outf, ushort* __restrict__ outb,
                      float* __restrict__ qkn, int M) {
    const int wid = threadIdx.x >> 6, lane = threadIdx.x & 63;
    const int n = blockIdx.x * 4 + wid;
    if (n >= M) return;
    long off = (long)n * 256 + lane * 4;
    const long stride = (long)M * 256;
    float4 a = *(const float4*)(P + off);
    float4 b = *(const float4*)(P + stride + off);
    float4 c = *(const float4*)(P + 2 * stride + off);
    float4 bs = *(const float4*)(bf2 + lane * 4);
    float rr[4] = { a.x + b.x + c.x + bs.x, a.y + b.y + c.y + bs.y,
                    a.z + b.z + c.z + bs.z, a.w + b.w + c.w + bs.w };
    float4 r4 = { rr[0], rr[1], rr[2], rr[3] };
    *(float4*)(outf + off) = r4;
    ushort4 o4 = { f2bf(rr[0]), f2bf(rr[1]), f2bf(rr[2]), f2bf(rr[3]) };
    *(ushort4*)(outb + off) = o4;
    float acc[24];
#pragma unroll
    for (int j = 0; j < 24; ++j) acc[j] = 0.f;
#pragma unroll
    for (int i = 0; i < 4; ++i) {
        const float* wr = Wqk2 + (long)(lane * 4 + i) * 24;
        float hv = rr[i];
#pragma unroll
        for (int j = 0; j < 24; ++j) acc[j] += hv * wr[j];
    }
#pragma unroll
    for (int j = 0; j < 24; ++j) {
        float v = wave_sum(acc[j]);
        if (lane == 0) qkn[(long)n * 24 + j] = v;
    }
}

// ================= attention (wave-per-node, no-max softmax, 4-slot pipelined gather) =================
__global__ __launch_bounds__(256)
void attn_kernel(const float* __restrict__ qkn, const ushort* __restrict__ xW,
                 const float* __restrict__ ae, const int* __restrict__ offs,
                 const int* __restrict__ csr, const int* __restrict__ srcv,
                 const int* __restrict__ etv, const float* __restrict__ bias,
                 ushort* __restrict__ out, int N, int ldx) {
    __shared__ float4 pk_sh[4][64];
    __shared__ float red[4][384];
    const int wid = threadIdx.x >> 6, lane = threadIdx.x & 63;
    const int n = blockIdx.x * 4 + wid;
    if (n >= N) return;
    const int e0 = offs[n];
    const int deg = offs[n + 1] - e0;
    const float* qd = qkn + (long)n * 24;

    float acc[6] = {0.f, 0.f, 0.f, 0.f, 0.f, 0.f};
    float ps0 = 0.f, ps1 = 0.f, ps2 = 0.f;

    for (int base = 0; base < deg; base += 64) {
        int cnt2 = deg - base; if (cnt2 > 64) cnt2 = 64;
        if (lane < cnt2) {
            int eid = csr[e0 + base + lane];
            int s_ = srcv[eid], t_ = etv[eid];
            const float* qs = qkn + (long)s_ * 24 + t_ * 6;
            const float* a3 = ae + (long)eid * 3;
            float v0 = qd[t_ * 6 + 0] + qs[3] + a3[0];
            float v1 = qd[t_ * 6 + 1] + qs[4] + a3[1];
            float v2 = qd[t_ * 6 + 2] + qs[5] + a3[2];
            v0 = v0 > 0.f ? v0 : 0.2f * v0;
            v1 = v1 > 0.f ? v1 : 0.2f * v1;
            v2 = v2 > 0.f ? v2 : 0.2f * v2;
            float p0 = __expf(v0), p1 = __expf(v1), p2 = __expf(v2);
            pk_sh[wid][lane] = make_float4(p0, p1, p2, __int_as_float((s_ << 2) | t_));
            ps0 += p0; ps1 += p1; ps2 += p2;
        }
        wave_sync();
        float4 pk0 = {0,0,0,0}, pk1 = {0,0,0,0}, pk2 = {0,0,0,0}, pk3 = {0,0,0,0};
        uint a0 = 0, b0 = 0, c0 = 0, a1 = 0, b1 = 0, c1 = 0;
        uint a2 = 0, b2 = 0, c2 = 0, a3 = 0, b3 = 0, c3 = 0;
#define LDE(S, J) { pk##S = pk_sh[wid][J]; int pk_ = __float_as_int(pk##S.w); \
    const uint* xr = (const uint*)(xW + (long)(pk_ >> 2) * ldx + (pk_ & 3) * 384); \
    a##S = xr[lane]; b##S = xr[lane + 64]; c##S = xr[lane + 128]; }
#define ACCE(S) { \
    acc[0] += pk##S.x * bf2f((ushort)(a##S & 0xffffu)); \
    acc[1] += pk##S.x * bf2f((ushort)(a##S >> 16)); \
    acc[2] += pk##S.y * bf2f((ushort)(b##S & 0xffffu)); \
    acc[3] += pk##S.y * bf2f((ushort)(b##S >> 16)); \
    acc[4] += pk##S.z * bf2f((ushort)(c##S & 0xffffu)); \
    acc[5] += pk##S.z * bf2f((ushort)(c##S >> 16)); }
        if (0 < cnt2) LDE(0, 0);
        if (1 < cnt2) LDE(1, 1);
        if (2 < cnt2) LDE(2, 2);
        if (3 < cnt2) LDE(3, 3);
        for (int j = 0; j < cnt2; j += 4) {
            { ACCE(0); if (j + 4 < cnt2) LDE(0, j + 4); }
            if (j + 1 < cnt2) { ACCE(1); if (j + 5 < cnt2) LDE(1, j + 5); }
            if (j + 2 < cnt2) { ACCE(2); if (j + 6 < cnt2) LDE(2, j + 6); }
            if (j + 3 < cnt2) { ACCE(3); if (j + 7 < cnt2) LDE(3, j + 7); }
        }
#undef LDE
#undef ACCE
        wave_sync();
    }
    ps0 = wave_sum(ps0); ps1 = wave_sum(ps1); ps2 = wave_sum(ps2);
    float i0 = 1.f / fmaxf(ps0, 1e-16f);
    float i1 = 1.f / fmaxf(ps1, 1e-16f);
    float i2 = 1.f / fmaxf(ps2, 1e-16f);
    red[wid][2 * lane]           = acc[0] * i0;
    red[wid][2 * lane + 1]       = acc[1] * i0;
    red[wid][128 + 2 * lane]     = acc[2] * i1;
    red[wid][128 + 2 * lane + 1] = acc[3] * i1;
    red[wid][256 + 2 * lane]     = acc[4] * i2;
    red[wid][256 + 2 * lane + 1] = acc[5] * i2;
    wave_sync();
    for (int o = lane; o < 128; o += 64) {
        float v = (red[wid][o] + red[wid][128 + o] + red[wid][256 + o]) * (1.f / 3.f) + bias[o];
        out[(long)n * 128 + o] = f2bf(v);
    }
}

// layer 2: Z-accumulation (wave-per-node, no-max softmax, 4-slot pipelined gather)
__global__ __launch_bounds__(256)
void attn2_kernel(const float* __restrict__ qkn, const ushort* __restrict__ hbf,
                  const float* __restrict__ ae, const int* __restrict__ offs,
                  const int* __restrict__ csr, const int* __restrict__ srcv,
                  const int* __restrict__ etv, ushort* __restrict__ Z, int N) {
    __shared__ float4 pk_sh[4][64];
    const int wid = threadIdx.x >> 6, lane = threadIdx.x & 63;
    const int n = blockIdx.x * 4 + wid;
    if (n >= N) return;
    const int e0 = offs[n];
    const int deg = offs[n + 1] - e0;
    const float* qd = qkn + (long)n * 24;

    float acc[48];
#pragma unroll
    for (int i = 0; i < 48; ++i) acc[i] = 0.f;
    float ps0 = 0.f, ps1 = 0.f, ps2 = 0.f;

    for (int base = 0; base < deg; base += 64) {
        int cnt2 = deg - base; if (cnt2 > 64) cnt2 = 64;
        if (lane < cnt2) {
            int eid = csr[e0 + base + lane];
            int s_ = srcv[eid], t_ = etv[eid];
            const float* qs = qkn + (long)s_ * 24 + t_ * 6;
            const float* a3 = ae + (long)eid * 3;
            float v0 = qd[t_ * 6 + 0] + qs[3] + a3[0];
            float v1 = qd[t_ * 6 + 1] + qs[4] + a3[1];
            float v2 = qd[t_ * 6 + 2] + qs[5] + a3[2];
            v0 = v0 > 0.f ? v0 : 0.2f * v0;
            v1 = v1 > 0.f ? v1 : 0.2f * v1;
            v2 = v2 > 0.f ? v2 : 0.2f * v2;
            float p0 = __expf(v0), p1 = __expf(v1), p2 = __expf(v2);
            pk_sh[wid][lane] = make_float4(p0, p1, p2, __int_as_float((s_ << 2) | t_));
            ps0 += p0; ps1 += p1; ps2 += p2;
        }
        wave_sync();
        float4 pk0 = {0,0,0,0}, pk1 = {0,0,0,0}, pk2 = {0,0,0,0}, pk3 = {0,0,0,0};
        uint2 v0_ = {0,0}, v1_ = {0,0}, v2_ = {0,0}, v3_ = {0,0};
#define LDE2(S, J) { pk##S = pk_sh[wid][J]; \
    v##S##_ = *(const uint2*)(hbf + ((long)(__float_as_int(pk##S.w) >> 2)) * 256 + lane * 4); }
#define UPDR(R) { \
    acc[(R)*4+0] += px * x0; acc[(R)*4+1] += px * x1; acc[(R)*4+2] += px * x2; acc[(R)*4+3] += px * x3; \
    acc[16+(R)*4+0] += py * x0; acc[16+(R)*4+1] += py * x1; acc[16+(R)*4+2] += py * x2; acc[16+(R)*4+3] += py * x3; \
    acc[32+(R)*4+0] += pz * x0; acc[32+(R)*4+1] += pz * x1; acc[32+(R)*4+2] += pz * x2; acc[32+(R)*4+3] += pz * x3; }
#define ACC2(S) { int r_ = __float_as_int(pk##S.w) & 3; \
    float x0 = bf2f((ushort)(v##S##_.x & 0xffffu)), x1 = bf2f((ushort)(v##S##_.x >> 16)); \
    float x2 = bf2f((ushort)(v##S##_.y & 0xffffu)), x3 = bf2f((ushort)(v##S##_.y >> 16)); \
    float px = pk##S.x, py = pk##S.y, pz = pk##S.z; \
    if (r_ == 0) UPDR(0) else if (r_ == 1) UPDR(1) else if (r_ == 2) UPDR(2) else UPDR(3) }
        if (0 < cnt2) LDE2(0, 0);
        if (1 < cnt2) LDE2(1, 1);
        if (2 < cnt2) LDE2(2, 2);
        if (3 < cnt2) LDE2(3, 3);
        for (int j = 0; j < cnt2; j += 4) {
            { ACC2(0); if (j + 4 < cnt2) LDE2(0, j + 4); }
            if (j + 1 < cnt2) { ACC2(1); if (j + 5 < cnt2) LDE2(1, j + 5); }
            if (j + 2 < cnt2) { ACC2(2); if (j + 6 < cnt2) LDE2(2, j + 6); }
            if (j + 3 < cnt2) { ACC2(3); if (j + 7 < cnt2) LDE2(3, j + 7); }
        }
#undef LDE2
#undef UPDR
#undef ACC2
        wave_sync();
    }
    ps0 = wave_sum(ps0); ps1 = wave_sum(ps1); ps2 = wave_sum(ps2);
    float inv0 = 1.f / fmaxf(ps0, 1e-16f);
    float inv1 = 1.f / fmaxf(ps1, 1e-16f);
    float inv2 = 1.f / fmaxf(ps2, 1e-16f);
    ushort* zr = Z + (long)n * 3072 + lane * 4;
#pragma unroll
    for (int h = 0; h < 3; ++h) {
        float iv = (h == 0) ? inv0 : (h == 1 ? inv1 : inv2);
#pragma unroll
        for (int r = 0; r < 4; ++r) {
            const float* a4 = acc + h * 16 + r * 4;
            ushort4 o4 = { f2bf(a4[0] * iv), f2bf(a4[1] * iv),
                           f2bf(a4[2] * iv), f2bf(a4[3] * iv) };
            *(ushort4*)(zr + h * 1024 + r * 256) = o4;
        }
    }
}

// ---------------- final: hole-node softmax (hole_idx = b * (N/B), batch is sorted repeat) ----------------
__global__ void softmax_kernel(const float* __restrict__ h, int npb,
                               float* __restrict__ out, int B) {
    int b = blockIdx.x;
    int t = threadIdx.x;
    int lane = t & 63, wid = t >> 6;
    __shared__ float sm[4];
    __shared__ float ss[4];
    int row = b * npb;
    float v = h[(long)row * 256 + t];
    float m = v;
#pragma unroll
    for (int d = 32; d >= 1; d >>= 1) m = fmaxf(m, __shfl_xor(m, d));
    if (lane == 0) sm[wid] = m;
    __syncthreads();
    m = fmaxf(fmaxf(sm[0], sm[1]), fmaxf(sm[2], sm[3]));
    float ex = __expf(v - m);
    float s = ex;
#pragma unroll
    for (int d = 32; d >= 1; d >>= 1) s += __shfl_xor(s, d);
    if (lane == 0) ss[wid] = s;
    __syncthreads();
    s = ss[0] + ss[1] + ss[2] + ss[3];
    out[(long)b * 256 + t] = ex / s;
}

// ---------------- host ----------------
extern "C" void kernel_launch(void* const* d_in, const int* in_sizes, int n_in,
                              void* d_out, int out_size, void* d_ws, size_t ws_size,
                              hipStream_t stream) {
    const float* x   = (const float*)d_in[0];
    const int*   ei  = (const int*)d_in[1];
    const int*   ety = (const int*)d_in[2];
    const float* ea  = (const float*)d_in[3];

    const int N = in_sizes[0] / 768;
    const int E = in_sizes[2];
    const int B = out_size / 256;

    static const int CIN[4]  = {768, 256, 256, 256};
    static const int COUT[4] = {128, 384, 128, 128};
    static const int NCC[4]  = {1536, 4608, 1536, 1536};

    const float *Wp[4], *qp[4], *kp[4], *lep[4], *ep[4], *bp[4], *lwp[4], *lbp[4];
    for (int l = 0; l < 4; ++l) {
        Wp[l]  = (const float*)d_in[5 + 6 * l];
        qp[l]  = (const float*)d_in[6 + 6 * l];
        kp[l]  = (const float*)d_in[7 + 6 * l];
        lep[l] = (const float*)d_in[8 + 6 * l];
        ep[l]  = (const float*)d_in[9 + 6 * l];
        bp[l]  = (const float*)d_in[10 + 6 * l];
        lwp[l] = (const float*)d_in[29 + 2 * l];
        lbp[l] = (const float*)d_in[30 + 2 * l];
    }

    char* ws = (char*)d_ws;
    size_t pos = 0;
    auto carve = [&](size_t bytes) -> char* {
        char* r = ws + pos;
        pos += (bytes + 255) & ~(size_t)255;
        return r;
    };
    ushort *Wt[4], *lwT[4];
    float* Wqk[4];
    for (int l = 0; l < 4; ++l) Wt[l]  = (ushort*)carve(l == 1 ? 0 : (size_t)2 * NCC[l] * CIN[l]);
    for (int l = 0; l < 4; ++l) lwT[l] = (ushort*)carve((size_t)2 * 384 * COUT[l]);
    for (int l = 0; l < 4; ++l) Wqk[l] = (float*)carve((size_t)4 * 24 * CIN[l]);
    float*  gbuf  = (float*)carve(4 * 24 * 4);
    float*  aeb   = (float*)carve((size_t)4 * E * 3 * 4);
    float*  qkn   = (float*)carve((size_t)N * 24 * 4);
    float*  qb1   = (float*)carve(24 * 4);
    float*  qb3   = (float*)carve(24 * 4);
    ushort* hbf   = (ushort*)carve((size_t)N * 768 * 2);
    ushort* xWb   = (ushort*)carve((size_t)N * 1536 * 2);   // also split-K fp32 partials
    ushort* Zb    = (ushort*)carve((size_t)N * 3072 * 2);
    ushort* A2    = (ushort*)carve((size_t)3072 * 384 * 2);
    ushort* W2T   = (ushort*)carve((size_t)256 * 3072 * 2);
    float*  bf2   = (float*)carve(256 * 4);
    ushort* convbf= (ushort*)carve((size_t)N * 384 * 2);
    float*  hbuf  = (float*)carve((size_t)N * 256 * 4);
    int* cnt  = (int*)carve((size_t)N * 4);
    int* cur  = (int*)carve((size_t)N * 4);
    int* offs = (int*)carve((size_t)(N + 1) * 4);
    int* csr  = (int*)carve((size_t)E * 4);

    hipMemsetAsync(cnt, 0, (size_t)((char*)cur - (char*)cnt) + (size_t)N * 4, stream);

    const int* dst = ei + E;
    deg_kernel<<<(E + 255) / 256, 256, 0, stream>>>(dst, cnt, E);
    scan_kernel<<<1, 1024, 0, stream>>>(cnt, offs, N);
    fill_kernel<<<(E + 255) / 256, 256, 0, stream>>>(dst, offs, cur, csr, E);

    PrepSArgs psa = { Wp[1], Wp[2], Wp[3], qp[1], qp[2], qp[3],
                      kp[1], kp[2], kp[3], Wqk[1], Wqk[2], Wqk[3],
                      lep[0], lep[1], lep[2], lep[3], ep[0], ep[1], ep[2], ep[3],
                      gbuf, bp[1], lwp[1], lbp[1], bf2 };
    preps_kernel<<<(3424 + 3) / 4, 256, 0, stream>>>(psa);

    long nCast = (long)N * 768;
    int nbCast = (int)((nCast / 4 + 255) / 256);
    int nbAe = (E + 255) / 256;
    PrepWArgs pw = { x, Wp[0], Wp[2], Wp[3], lwp[0], lwp[1], lwp[2], lwp[3], Wp[1],
                     hbf, Wt[0], Wt[2], Wt[3], lwT[0], lwT[1], lwT[2], lwT[3], A2,
                     ea, gbuf, aeb, Wqk[1], Wqk[3], lbp[0], lbp[2], qb1, qb3 };
    prepw_kernel<<<nbCast + nbAe + 4628, 256, 0, stream>>>(pw, nbCast, nCast, E, nbAe);

    gemm_bf16<1, 0, 0, 0><<<48, 256, 0, stream>>>(lwT[1], A2, (void*)W2T, nullptr, nullptr,
                                                  256, 384, 3072, 24, 48, 48, 384,
                                                  nullptr, nullptr, 0);

    const int nbm = (N + 127) / 128;
    for (int l = 0; l < 4; ++l) {
        if (l == 1) {
            attn2_kernel<<<(N + 3) / 4, 256, 0, stream>>>(qkn, hbf, aeb + (size_t)l * E * 3,
                                                          offs, csr, ei, ety, Zb, N);
            int nbase = nbm * 2, nwgS = nbase * 3;
            gemm_bf16<0, 0, 1, 0><<<nwgS, 256, 0, stream>>>(Zb, W2T, (void*)xWb, nullptr, nullptr,
                                                            N, 3072, 256, 2, nwgS, nbase, 1024,
                                                            nullptr, nullptr, 0);
            reduce3qk_kernel<<<(N + 3) / 4, 256, 0, stream>>>((const float*)xWb, bf2, Wqk[2],
                                                              hbuf, hbf, qkn, N);
        } else {
            int nbn1 = NCC[l] / 128, nwg1 = nbm * nbn1;
            gemm_bf16<1, 0, 0, 0><<<nwg1, 256, 0, stream>>>(hbf, Wt[l], (void*)xWb, nullptr,
                                                            nullptr, N, CIN[l], NCC[l], nbn1,
                                                            nwg1, nwg1, CIN[l],
                                                            nullptr, nullptr, 0);
            if (l == 0)
                qkx_kernel<<<(N + 3) / 4, 256, 0, stream>>>(xWb, qp[0], kp[0], qkn, N);
            attn_kernel<<<(N + 3) / 4, 256, 0, stream>>>(qkn, xWb, aeb + (size_t)l * E * 3,
                                                         offs, csr, ei, ety, bp[l], convbf, N, 1536);
            if (l == 3) {
                int nwg2 = nbm * 2;
                gemm_bf16<0, 0, 0, 0><<<nwg2, 256, 0, stream>>>(convbf, lwT[3], (void*)hbuf, nullptr,
                                                                lbp[3], N, 128, 256, 2, nwg2, nwg2, 128,
                                                                nullptr, nullptr, 0);
            } else {
                float* qbp = (l == 0) ? qb1 : qb3;
                int nwg2 = nbm * 3;
                gemm_bf16<0, 1, 0, 1><<<nwg2, 256, 0, stream>>>(convbf, lwT[l], (void*)hbuf, hbf,
                                                                lbp[l], N, 128, 256, 3, nwg2, nwg2, 128,
                                                                qkn, qbp, 256);
            }
        }
    }
    softmax_kernel<<<B, 256, 0, stream>>>(hbuf, N / B, (float*)d_out, B);
}